// Round 14
// baseline (300.611 us; speedup 1.0000x reference)
//
#include <hip/hip_runtime.h>
#include <hip/hip_bf16.h>

#define S_LEN 4096
#define EMB 768
#define NHEAD 8
#define HDIM 96

typedef short bf16x8 __attribute__((ext_vector_type(8)));
typedef float f32x4 __attribute__((ext_vector_type(4)));
typedef float f32x16 __attribute__((ext_vector_type(16)));

__device__ __forceinline__ short f2bf(float x) {
  union { float f; unsigned u; } v; v.f = x;
  unsigned r = v.u + 0x7fffu + ((v.u >> 16) & 1u);   // round-to-nearest-even
  return (short)(r >> 16);
}

__device__ __forceinline__ short f2bfh(float x) {
  union { __hip_bfloat16 h; short s; } u;
  u.h = __float2bfloat16(x);
  return u.s;
}

#define GLOAD_LDS16(gp, lp)                                              \
  __builtin_amdgcn_global_load_lds(                                      \
      (const __attribute__((address_space(1))) unsigned int*)(gp),       \
      (__attribute__((address_space(3))) unsigned int*)(lp), 16, 0, 0)

// ---------- fused prep (unchanged from r13) ----------
__global__ __launch_bounds__(256) void prep_kernel(const float* __restrict__ K,
                                                   const float* __restrict__ W,
                                                   const float* __restrict__ V,
                                                   short* __restrict__ KT,
                                                   short* __restrict__ Wb,
                                                   short* __restrict__ VTT) {
  __shared__ short tl[HDIM][68];
  int b = blockIdx.x;
  int tid = threadIdx.x;
  if (b < 1536) {
    int sb = b & 15; int b2 = b >> 4; int c = b2 % 6; b2 /= 6; int h = b2 & 7; int n = b2 >> 3;
    int s = sb * 256 + tid;
    const float* src = K + (size_t)(n * S_LEN + s) * EMB + h * HDIM + c * 16;
    float4 a0 = ((const float4*)src)[0];
    float4 a1 = ((const float4*)src)[1];
    float4 a2 = ((const float4*)src)[2];
    float4 a3 = ((const float4*)src)[3];
    bf16x8 r0, r1;
    r0[0]=f2bf(a0.x); r0[1]=f2bf(a0.y); r0[2]=f2bf(a0.z); r0[3]=f2bf(a0.w);
    r0[4]=f2bf(a1.x); r0[5]=f2bf(a1.y); r0[6]=f2bf(a1.z); r0[7]=f2bf(a1.w);
    r1[0]=f2bf(a2.x); r1[1]=f2bf(a2.y); r1[2]=f2bf(a2.z); r1[3]=f2bf(a2.w);
    r1[4]=f2bf(a3.x); r1[5]=f2bf(a3.y); r1[6]=f2bf(a3.z); r1[7]=f2bf(a3.w);
    short* dst = KT + ((size_t)((n * NHEAD + h) * 6 + c) * S_LEN + s) * 16;
    *(bf16x8*)dst = r0;
    *(bf16x8*)(dst + 8) = r1;
    return;
  }
  if (b < 1824) {
    int t = (b - 1536) * 256 + tid;
    size_t off = (size_t)t * 8;
    float4 a = *(const float4*)(W + off);
    float4 bq = *(const float4*)(W + off + 4);
    bf16x8 r;
    r[0]=f2bf(a.x);  r[1]=f2bf(a.y);  r[2]=f2bf(a.z);  r[3]=f2bf(a.w);
    r[4]=f2bf(bq.x); r[5]=f2bf(bq.y); r[6]=f2bf(bq.z); r[7]=f2bf(bq.w);
    *(bf16x8*)(Wb + off) = r;
    return;
  }
  int bb = b - 1824;   // 1024 blocks: (n, h, 64-key tile)
  int n = bb >> 9, h = (bb >> 6) & 7, st = bb & 63;
  int s0 = st * 64;
  const float* vp = V + ((size_t)(n * S_LEN + s0)) * EMB + h * HDIM;
  #pragma unroll
  for (int k = 0; k < 6; ++k) {
    int idx = k * 256 + tid;
    int fidx = idx * 4;
    int s = fidx / 96, d = fidx % 96;
    float4 a = *(const float4*)(vp + (size_t)s * EMB + d);
    tl[d + 0][s] = f2bf(a.x);
    tl[d + 1][s] = f2bf(a.y);
    tl[d + 2][s] = f2bf(a.z);
    tl[d + 3][s] = f2bf(a.w);
  }
  __syncthreads();
  short* op = VTT + (size_t)(n * NHEAD + h) * S_LEN * HDIM + (size_t)st * 64 * HDIM;
  #pragma unroll
  for (int i = 0; i < 3; ++i) {
    int u = i * 256 + tid;              // LDS-order unit 0..767
    int slice = u / 192;
    int rem = u - slice * 192;
    int dt = rem >> 6, hi2 = (rem >> 5) & 1, d5 = rem & 31;
    int d = dt * 32 + d5;
    int kb = 16 * slice + 4 * hi2;
    short4 lo = *(const short4*)&tl[d][kb];
    short4 hi4 = *(const short4*)&tl[d][kb + 8];
    bf16x8 r;
    r[0]=lo.x; r[1]=lo.y; r[2]=lo.z; r[3]=lo.w;
    r[4]=hi4.x; r[5]=hi4.y; r[6]=hi4.z; r[7]=hi4.w;
    *(bf16x8*)(op + (size_t)u * 8) = r;
  }
}

// ---------- flash attention: cross-block split-K, dual-s ILP, 4 waves/SIMD target ----------
// NKG key-groups as SEPARATE blocks (grid NKG*512): block L -> kg = L>>9, base = L&511,
// h = base&7 (XCD map), n, qt. 4 waves x 32 q-rows; dual-s QK (12 independent MFMA+loads).
// Register diet for the 128-reg/4-waves-per-SIMD cap: V via global_load_lds (0 staging regs),
// l via in-lane adds during exp (col-layout; split-K partials consume it directly, no
// broadcast), no lacc/vones MFMA. acc 48 + s0/s1 32 + qf 24 + misc ~16 ~= 121 <= 128.
// Fixed-max softmax (scale-invariant) -> partials additive: O = sum O_kg / sum l_kg.
// NKG=1 fallback (ws too small): direct Xb write with per-wave LDS l-broadcast.
template<int NKG>
__global__ __launch_bounds__(256, 4) void attn_kernel(const float* __restrict__ Q,
                                                      const short* __restrict__ KT,
                                                      const short* __restrict__ VTT,
                                                      short* __restrict__ Xb,
                                                      float* __restrict__ Op,
                                                      float* __restrict__ lp) {
  __shared__ __align__(16) char smem[24576];
  constexpr int KEYS = S_LEN / NKG;
  constexpr int ITERS = KEYS / 64;
  int L = blockIdx.x;
  int bb = L & 511;
  int kg = L >> 9;
  int h = bb & 7, j = bb >> 3;
  int n = j >> 5, qt = j & 31;
  int q0 = qt * 128;
  int tid = threadIdx.x;
  int w = tid >> 6, lane = tid & 63, l31 = lane & 31, hi = lane >> 5;

  const float kAdj = 0.14724512f;  // (1/sqrt(96)) * log2(e), folded into Q
  bf16x8 qf[6];
  {
    const float* qp = Q + ((size_t)(n * S_LEN + q0 + w * 32 + l31)) * EMB + h * HDIM + 8 * hi;
    #pragma unroll
    for (int c = 0; c < 6; ++c) {
      float4 a = *(const float4*)(qp + 16 * c);
      float4 bq = *(const float4*)(qp + 16 * c + 4);
      bf16x8 r;
      r[0]=f2bf(a.x*kAdj);  r[1]=f2bf(a.y*kAdj);  r[2]=f2bf(a.z*kAdj);  r[3]=f2bf(a.w*kAdj);
      r[4]=f2bf(bq.x*kAdj); r[5]=f2bf(bq.y*kAdj); r[6]=f2bf(bq.z*kAdj); r[7]=f2bf(bq.w*kAdj);
      qf[c] = r;
    }
  }

  const short* gK = KT + (size_t)(n * NHEAD + h) * 6 * S_LEN * 16
                       + (size_t)kg * KEYS * 16 + l31 * 16 + 8 * hi;
  const short* gVt = VTT + (size_t)(n * NHEAD + h) * S_LEN * HDIM
                        + (size_t)kg * KEYS * HDIM + (size_t)(w * 3) * 512 + lane * 8;
  char* ldsw = smem + w * 3072;
  int vrd = hi * 512 + l31 * 16;

  // prologue: stage tile0 -> buf0
  #pragma unroll
  for (int i = 0; i < 3; ++i)
    GLOAD_LDS16(gVt + i * 512, ldsw + i * 1024);
  __syncthreads();

  f32x16 o[3];
  #pragma unroll
  for (int dt = 0; dt < 3; ++dt) o[dt] = (f32x16){};
  float tsl = 0.f;

  int cur = 0;
  #pragma unroll 1
  for (int t = 0; t < ITERS; ++t) {
    if (t < ITERS - 1) {
      const short* src = gVt + (size_t)(t + 1) * 64 * HDIM;
      char* dst = ldsw + (cur ^ 1) * 12288;
      #pragma unroll
      for (int i = 0; i < 3; ++i)
        GLOAD_LDS16(src + i * 512, dst + i * 1024);
    }
    int k0 = t * 64;

    // ---- QK^T both 32-key subtiles (12 independent loads + MFMA) ----
    f32x16 s0 = (f32x16){}, s1 = (f32x16){};
    __builtin_amdgcn_s_setprio(1);
    #pragma unroll
    for (int c = 0; c < 6; ++c) {
      bf16x8 kf = *(const bf16x8*)(gK + ((size_t)c * S_LEN + k0) * 16);
      s0 = __builtin_amdgcn_mfma_f32_32x32x16_bf16(kf, qf[c], s0, 0, 0, 0);
    }
    #pragma unroll
    for (int c = 0; c < 6; ++c) {
      bf16x8 kf = *(const bf16x8*)(gK + ((size_t)c * S_LEN + k0 + 32) * 16);
      s1 = __builtin_amdgcn_mfma_f32_32x32x16_bf16(kf, qf[c], s1, 0, 0, 0);
    }
    __builtin_amdgcn_s_setprio(0);

    // ---- P = 2^score; accumulate row-sum (col-layout) in-lane ----
    #pragma unroll
    for (int r = 0; r < 16; ++r) { s0[r] = __builtin_amdgcn_exp2f(s0[r]); tsl += s0[r]; }
    #pragma unroll
    for (int r = 0; r < 16; ++r) { s1[r] = __builtin_amdgcn_exp2f(s1[r]); tsl += s1[r]; }

    // ---- pack (identity) + PV per 16-key slice ----
    const char* vbl = smem + cur * 12288;
    #pragma unroll
    for (int ksub = 0; ksub < 2; ++ksub) {
      const f32x16& s = ksub ? s1 : s0;
      #pragma unroll
      for (int ks = 0; ks < 2; ++ks) {
        unsigned d0, d1, d2, d3;
        asm("v_cvt_pk_bf16_f32 %0, %1, %2" : "=v"(d0) : "v"(s[8*ks+0]), "v"(s[8*ks+1]));
        asm("v_cvt_pk_bf16_f32 %0, %1, %2" : "=v"(d1) : "v"(s[8*ks+2]), "v"(s[8*ks+3]));
        asm("v_cvt_pk_bf16_f32 %0, %1, %2" : "=v"(d2) : "v"(s[8*ks+4]), "v"(s[8*ks+5]));
        asm("v_cvt_pk_bf16_f32 %0, %1, %2" : "=v"(d3) : "v"(s[8*ks+6]), "v"(s[8*ks+7]));
        union { unsigned u[4]; bf16x8 v; } pu;
        pu.u[0] = d0; pu.u[1] = d1; pu.u[2] = d2; pu.u[3] = d3;
        int slice = 2 * ksub + ks;
        __builtin_amdgcn_s_setprio(1);
        #pragma unroll
        for (int dt = 0; dt < 3; ++dt) {
          bf16x8 vf = *(const bf16x8*)(vbl + (slice * 3 + dt) * 1024 + vrd);
          o[dt] = __builtin_amdgcn_mfma_f32_32x32x16_bf16(pu.v, vf, o[dt], 0, 0, 0);
        }
        __builtin_amdgcn_s_setprio(0);
      }
    }
    __syncthreads();
    cur ^= 1;
  }

  // row l (col-layout: row index = l31): combine the two hi-halves
  float lcol = tsl + __shfl_xor(tsl, 32, 64);

  if constexpr (NKG > 1) {
    // ---- write partials: O (row-layout) + l (col-layout, row=l31) ----
    float* op = Op + (size_t)L * 12288;
    #pragma unroll
    for (int p = 0; p < 4; ++p) {
      #pragma unroll
      for (int jj = 0; jj < 4; ++jj) {
        int qrow = w * 32 + 8 * p + 4 * hi + jj;
        op[(size_t)qrow * 96 + l31]      = o[0][4*p+jj];
        op[(size_t)qrow * 96 + 32 + l31] = o[1][4*p+jj];
        op[(size_t)qrow * 96 + 64 + l31] = o[2][4*p+jj];
      }
    }
    if (hi == 0) lp[(size_t)L * 128 + w * 32 + l31] = lcol;
  } else {
    // ---- direct: broadcast 1/l col->row via LDS, normalize, write Xb ----
    __syncthreads();
    float* bcf = (float*)smem;
    if (hi == 0) bcf[w * 32 + l31] = 1.0f / lcol;
    __syncthreads();
    #pragma unroll
    for (int p = 0; p < 4; ++p) {
      #pragma unroll
      for (int jj = 0; jj < 4; ++jj) {
        int qr = 8 * p + 4 * hi + jj;
        float iv = bcf[w * 32 + qr];
        short* xp = Xb + ((size_t)(n * S_LEN + q0 + w * 32 + qr)) * EMB + h * HDIM + l31;
        xp[0]  = f2bfh(o[0][4*p+jj] * iv);
        xp[32] = f2bfh(o[1][4*p+jj] * iv);
        xp[64] = f2bfh(o[2][4*p+jj] * iv);
      }
    }
  }
}

// ---------- split-K combine: Xb = (sum_kg O) / (sum_kg l), bf16 ----------
__global__ __launch_bounds__(256) void combine_kernel(const float* __restrict__ Op,
                                                      const float* __restrict__ lp,
                                                      short* __restrict__ Xb,
                                                      int nkg) {
  int b = blockIdx.x;
  int h = b & 7, j = b >> 3, n = j >> 5, qt = j & 31;
  int q0 = qt * 128;
  int tid = threadIdx.x;
  #pragma unroll 1
  for (int i = 0; i < 12; ++i) {
    int idx = (i * 256 + tid) * 4;
    int qr = idx / 96, d = idx - qr * 96;
    float ax = 0.f, ay = 0.f, az = 0.f, aw = 0.f, l = 0.f;
    for (int kg = 0; kg < nkg; ++kg) {
      size_t blk = (size_t)(kg * 512 + b);
      float4 v = *(const float4*)(Op + blk * 12288 + idx);
      ax += v.x; ay += v.y; az += v.z; aw += v.w;
      l += lp[blk * 128 + qr];
    }
    float iv = 1.0f / l;
    short4 r;
    r.x = f2bfh(ax * iv); r.y = f2bfh(ay * iv);
    r.z = f2bfh(az * iv); r.w = f2bfh(aw * iv);
    *(short4*)(Xb + ((size_t)(n * S_LEN + q0 + qr)) * EMB + h * HDIM + d) = r;
  }
}

// ---------- FC: out[m][j] = sum_k X[m][k] * W[j][k] + b[j] ----------
__global__ __launch_bounds__(256) void fc_kernel(const short* __restrict__ Xb,
                                                 const short* __restrict__ Wb,
                                                 const float* __restrict__ bias,
                                                 float* __restrict__ out) {
  int m0 = blockIdx.x * 64, j0 = blockIdx.y * 64;
  int tid = threadIdx.x;
  int w = tid >> 6, lane = tid & 63, lr = lane & 15, lg = lane >> 4;
  f32x4 acc[4];
  #pragma unroll
  for (int jt = 0; jt < 4; ++jt) acc[jt] = (f32x4){0.f, 0.f, 0.f, 0.f};
  const short* xp = Xb + (size_t)(m0 + w * 16 + lr) * EMB + 8 * lg;
  const short* wp = Wb + (size_t)(j0 + lr) * EMB + 8 * lg;
  #pragma unroll 1
  for (int kt = 0; kt < 24; ++kt) {
    bf16x8 a = *(const bf16x8*)(xp + kt * 32);
    #pragma unroll
    for (int jt = 0; jt < 4; ++jt) {
      bf16x8 bw = *(const bf16x8*)(wp + (size_t)(jt * 16) * EMB + kt * 32);
      acc[jt] = __builtin_amdgcn_mfma_f32_16x16x32_bf16(a, bw, acc[jt], 0, 0, 0);
    }
  }
  #pragma unroll
  for (int jt = 0; jt < 4; ++jt) {
    float bb = bias[j0 + jt * 16 + lr];
    #pragma unroll
    for (int i = 0; i < 4; ++i)
      out[(size_t)(m0 + w * 16 + 4 * lg + i) * EMB + j0 + jt * 16 + lr] = acc[jt][i] + bb;
  }
}

extern "C" void kernel_launch(void* const* d_in, const int* in_sizes, int n_in,
                              void* d_out, int out_size, void* d_ws, size_t ws_size,
                              hipStream_t stream) {
  (void)in_sizes; (void)n_in; (void)out_size;
  const float* V = (const float*)d_in[0];
  const float* K = (const float*)d_in[1];
  const float* Q = (const float*)d_in[2];
  const float* W = (const float*)d_in[3];
  const float* B = (const float*)d_in[4];
  float* out = (float*)d_out;
  // ws layout (shorts): KT[6291456] | VTT[6291456] | Wb[589824] | Xb[6291456] | partials(f32)
  short* KT  = (short*)d_ws;
  short* VTT = KT + 6291456;
  short* Wb  = VTT + 6291456;
  short* Xb  = Wb + 589824;
  size_t base_bytes = (size_t)(6291456 + 6291456 + 589824 + 6291456) * 2;
  size_t part_bytes = (size_t)2 * 512 * (12288 + 128) * 4;
  prep_kernel<<<2848, 256, 0, stream>>>(K, W, V, KT, Wb, VTT);
  if (ws_size >= base_bytes + part_bytes) {
    float* Op = (float*)((char*)d_ws + base_bytes);
    float* lp = Op + (size_t)2 * 512 * 12288;
    attn_kernel<2><<<1024, 256, 0, stream>>>(Q, KT, VTT, Xb, Op, lp);
    combine_kernel<<<512, 256, 0, stream>>>(Op, lp, Xb, 2);
  } else {
    attn_kernel<1><<<512, 256, 0, stream>>>(Q, KT, VTT, Xb, nullptr, nullptr);
  }
  fc_kernel<<<dim3(128, 12), 256, 0, stream>>>(Xb, Wb, B, out);
}

// Round 15
// 217.026 us; speedup vs baseline: 1.3851x; 1.3851x over previous
//
#include <hip/hip_runtime.h>
#include <hip/hip_bf16.h>

#define S_LEN 4096
#define EMB 768
#define NHEAD 8
#define HDIM 96

typedef short bf16x8 __attribute__((ext_vector_type(8)));
typedef float f32x4 __attribute__((ext_vector_type(4)));
typedef float f32x16 __attribute__((ext_vector_type(16)));

__device__ __forceinline__ short f2bf(float x) {
  union { float f; unsigned u; } v; v.f = x;
  unsigned r = v.u + 0x7fffu + ((v.u >> 16) & 1u);   // round-to-nearest-even
  return (short)(r >> 16);
}

__device__ __forceinline__ short f2bfh(float x) {
  union { __hip_bfloat16 h; short s; } u;
  u.h = __float2bfloat16(x);
  return u.s;
}

#define GLOAD_LDS16(gp, lp)                                              \
  __builtin_amdgcn_global_load_lds(                                      \
      (const __attribute__((address_space(1))) unsigned int*)(gp),       \
      (__attribute__((address_space(3))) unsigned int*)(lp), 16, 0, 0)

// ---------- fused prep ----------
// blocks [0,288): W -> bf16.
// blocks [288,1312): one (n,h,64-key tile) each -> KVT tile of 24KB:
//   K part (12KB): unit u(16B) = c*128 + key*2 + h8 holds K[key][16c+8*h8 .. +7]
//     -> attn QK A-frag = contiguous-1KB/wave ds_read_b128 (conflict-free).
//   V part (12KB): r13 lane-linear sigma layout (sigma = swap key bits 2<->3,
//     matches 32x32 MFMA C/D slots so P packs identity into the PV A-frag).
// Both staged in attn by global_load_lds (LDS-linear 1KB units).
__global__ __launch_bounds__(256) void prep_kernel(const float* __restrict__ K,
                                                   const float* __restrict__ W,
                                                   const float* __restrict__ V,
                                                   short* __restrict__ KVT,
                                                   short* __restrict__ Wb) {
  __shared__ short tlbuf[6656];
  int b = blockIdx.x;
  int tid = threadIdx.x;
  if (b < 288) {
    int t = b * 256 + tid;
    size_t off = (size_t)t * 8;
    float4 a = *(const float4*)(W + off);
    float4 bq = *(const float4*)(W + off + 4);
    bf16x8 r;
    r[0]=f2bf(a.x);  r[1]=f2bf(a.y);  r[2]=f2bf(a.z);  r[3]=f2bf(a.w);
    r[4]=f2bf(bq.x); r[5]=f2bf(bq.y); r[6]=f2bf(bq.z); r[7]=f2bf(bq.w);
    *(bf16x8*)(Wb + off) = r;
    return;
  }
  int bb = b - 288;   // 1024 blocks: (n, h, 64-key tile)
  int n = bb >> 9, h = (bb >> 6) & 7, st = bb & 63;
  int s0 = st * 64;
  short* KVp = KVT + ((size_t)((n * NHEAD + h) * 64 + st)) * 12288;

  // ---- K phase: tlK[s][d] with row pad 104 ----
  const float* kp = K + ((size_t)(n * S_LEN + s0)) * EMB + h * HDIM;
  #pragma unroll
  for (int k = 0; k < 6; ++k) {
    int idx = k * 256 + tid;
    int fidx = idx * 4;
    int s = fidx / 96, d = fidx % 96;
    float4 a = *(const float4*)(kp + (size_t)s * EMB + d);
    short* t4 = &tlbuf[s * 104 + d];
    t4[0] = f2bf(a.x); t4[1] = f2bf(a.y); t4[2] = f2bf(a.z); t4[3] = f2bf(a.w);
  }
  __syncthreads();
  #pragma unroll
  for (int i = 0; i < 3; ++i) {
    int u = i * 256 + tid;           // K unit 0..767
    int c = u >> 7, rem = u & 127, key = rem >> 1, h8 = rem & 1;
    int db = c * 16 + h8 * 8;
    short4 lo = *(const short4*)&tlbuf[key * 104 + db];
    short4 hi4 = *(const short4*)&tlbuf[key * 104 + db + 4];
    bf16x8 r;
    r[0]=lo.x; r[1]=lo.y; r[2]=lo.z; r[3]=lo.w;
    r[4]=hi4.x; r[5]=hi4.y; r[6]=hi4.z; r[7]=hi4.w;
    *(bf16x8*)(KVp + (size_t)u * 8) = r;
  }
  __syncthreads();

  // ---- V phase: tl[d][s] with row pad 68 (sigma layout, r13-validated) ----
  const float* vp = V + ((size_t)(n * S_LEN + s0)) * EMB + h * HDIM;
  #pragma unroll
  for (int k = 0; k < 6; ++k) {
    int idx = k * 256 + tid;
    int fidx = idx * 4;
    int s = fidx / 96, d = fidx % 96;
    float4 a = *(const float4*)(vp + (size_t)s * EMB + d);
    tlbuf[(d + 0) * 68 + s] = f2bf(a.x);
    tlbuf[(d + 1) * 68 + s] = f2bf(a.y);
    tlbuf[(d + 2) * 68 + s] = f2bf(a.z);
    tlbuf[(d + 3) * 68 + s] = f2bf(a.w);
  }
  __syncthreads();
  #pragma unroll
  for (int i = 0; i < 3; ++i) {
    int u = i * 256 + tid;           // V unit 0..767
    int slice = u / 192;
    int rem = u - slice * 192;
    int dt = rem >> 6, hi2 = (rem >> 5) & 1, d5 = rem & 31;
    int d = dt * 32 + d5;
    int kb = 16 * slice + 4 * hi2;
    short4 lo = *(const short4*)&tlbuf[d * 68 + kb];
    short4 hi4 = *(const short4*)&tlbuf[d * 68 + kb + 8];
    bf16x8 r;
    r[0]=lo.x; r[1]=lo.y; r[2]=lo.z; r[3]=lo.w;
    r[4]=hi4.x; r[5]=hi4.y; r[6]=hi4.z; r[7]=hi4.w;
    *(bf16x8*)(KVp + 6144 + (size_t)u * 8) = r;
  }
}

// ---------- flash attention: K+V in LDS (gload_lds), dual-s, split-K across blocks ----------
// grid = NKG*512; L -> kg = L>>9, bb = L&511, h = bb&7 (XCD map), n, qt. 4 waves x 32 q.
// Per 64-key tile: one fused 24KB KVT stage (6 gload16/wave, zero staging regs),
// then dual-s QK (12 independent MFMA) from K-LDS + PV from V-LDS. All LDS reads are
// contiguous-1KB/wave ds_read_b128 -> conflict-free. l in-lane (col-layout, r14-validated).
// Fixed-max softmax (scale-invariant) -> split-K additive: O = sum O_kg / sum l_kg.
// __launch_bounds__(256,3): 170-reg cap fits dual-s (~85 arch + 48 acc), LDS 48KB ->
// 3 blocks/CU = 12 waves/CU = 3/SIMD. ILP x TLP = 36 vs r11's 24.
template<int NKG>
__global__ __launch_bounds__(256, 3) void attn_kernel(const float* __restrict__ Q,
                                                      const short* __restrict__ KVT,
                                                      short* __restrict__ Xb,
                                                      float* __restrict__ Op,
                                                      float* __restrict__ lp) {
  __shared__ __align__(16) char smem[49152];
  constexpr int ITERS = S_LEN / NKG / 64;
  int L = blockIdx.x;
  int bb = L & 511;
  int kg = L >> 9;
  int h = bb & 7, j = bb >> 3;
  int n = j >> 5, qt = j & 31;
  int q0 = qt * 128;
  int tid = threadIdx.x;
  int w = tid >> 6, lane = tid & 63, l31 = lane & 31, hi = lane >> 5;

  const float kAdj = 0.14724512f;  // (1/sqrt(96)) * log2(e), folded into Q
  bf16x8 qf[6];
  {
    const float* qp = Q + ((size_t)(n * S_LEN + q0 + w * 32 + l31)) * EMB + h * HDIM + 8 * hi;
    #pragma unroll
    for (int c = 0; c < 6; ++c) {
      float4 a = *(const float4*)(qp + 16 * c);
      float4 bq = *(const float4*)(qp + 16 * c + 4);
      bf16x8 r;
      r[0]=f2bf(a.x*kAdj);  r[1]=f2bf(a.y*kAdj);  r[2]=f2bf(a.z*kAdj);  r[3]=f2bf(a.w*kAdj);
      r[4]=f2bf(bq.x*kAdj); r[5]=f2bf(bq.y*kAdj); r[6]=f2bf(bq.z*kAdj); r[7]=f2bf(bq.w*kAdj);
      qf[c] = r;
    }
  }

  // KVT stream for this block's key range; per-wave staging share = units w*6..w*6+5
  const short* gKV = KVT + ((size_t)((n * NHEAD + h) * 64 + kg * ITERS)) * 12288
                        + (size_t)(w * 6) * 512 + lane * 8;
  char* ldsw = smem + w * 6144;

  // prologue: stage tile0 -> buf0
  #pragma unroll
  for (int i = 0; i < 6; ++i)
    GLOAD_LDS16(gKV + i * 512, ldsw + i * 1024);
  __syncthreads();

  f32x16 o[3];
  #pragma unroll
  for (int dt = 0; dt < 3; ++dt) o[dt] = (f32x16){};
  float tsl = 0.f;

  int cur = 0;
  #pragma unroll 1
  for (int t = 0; t < ITERS; ++t) {
    if (t < ITERS - 1) {
      const short* src = gKV + (size_t)(t + 1) * 12288;
      char* dst = ldsw + (cur ^ 1) * 24576;
      #pragma unroll
      for (int i = 0; i < 6; ++i)
        GLOAD_LDS16(src + i * 512, dst + i * 1024);
    }
    const char* kbl = smem + cur * 24576;          // K part
    const char* vbl = kbl + 12288;                 // V part

    // ---- QK^T both 32-key subtiles (12 independent ds_read+MFMA) ----
    f32x16 s0 = (f32x16){}, s1 = (f32x16){};
    __builtin_amdgcn_s_setprio(1);
    #pragma unroll
    for (int c = 0; c < 6; ++c) {
      bf16x8 kf = *(const bf16x8*)(kbl + c * 2048 + l31 * 32 + hi * 16);
      s0 = __builtin_amdgcn_mfma_f32_32x32x16_bf16(kf, qf[c], s0, 0, 0, 0);
    }
    #pragma unroll
    for (int c = 0; c < 6; ++c) {
      bf16x8 kf = *(const bf16x8*)(kbl + c * 2048 + 1024 + l31 * 32 + hi * 16);
      s1 = __builtin_amdgcn_mfma_f32_32x32x16_bf16(kf, qf[c], s1, 0, 0, 0);
    }
    __builtin_amdgcn_s_setprio(0);

    // ---- P = 2^score; in-lane row-sum (col-layout) ----
    #pragma unroll
    for (int r = 0; r < 16; ++r) { s0[r] = __builtin_amdgcn_exp2f(s0[r]); tsl += s0[r]; }
    #pragma unroll
    for (int r = 0; r < 16; ++r) { s1[r] = __builtin_amdgcn_exp2f(s1[r]); tsl += s1[r]; }

    // ---- pack (identity) + PV per 16-key slice ----
    #pragma unroll
    for (int ksub = 0; ksub < 2; ++ksub) {
      const f32x16& s = ksub ? s1 : s0;
      #pragma unroll
      for (int ks = 0; ks < 2; ++ks) {
        unsigned d0, d1, d2, d3;
        asm("v_cvt_pk_bf16_f32 %0, %1, %2" : "=v"(d0) : "v"(s[8*ks+0]), "v"(s[8*ks+1]));
        asm("v_cvt_pk_bf16_f32 %0, %1, %2" : "=v"(d1) : "v"(s[8*ks+2]), "v"(s[8*ks+3]));
        asm("v_cvt_pk_bf16_f32 %0, %1, %2" : "=v"(d2) : "v"(s[8*ks+4]), "v"(s[8*ks+5]));
        asm("v_cvt_pk_bf16_f32 %0, %1, %2" : "=v"(d3) : "v"(s[8*ks+6]), "v"(s[8*ks+7]));
        union { unsigned u[4]; bf16x8 v; } pu;
        pu.u[0] = d0; pu.u[1] = d1; pu.u[2] = d2; pu.u[3] = d3;
        int slice = 2 * ksub + ks;
        __builtin_amdgcn_s_setprio(1);
        #pragma unroll
        for (int dt = 0; dt < 3; ++dt) {
          bf16x8 vf = *(const bf16x8*)(vbl + (slice * 3 + dt) * 1024 + hi * 512 + l31 * 16);
          o[dt] = __builtin_amdgcn_mfma_f32_32x32x16_bf16(pu.v, vf, o[dt], 0, 0, 0);
        }
        __builtin_amdgcn_s_setprio(0);
      }
    }
    __syncthreads();     // staging drained (issued before compute); buffers swap
    cur ^= 1;
  }

  float lcol = tsl + __shfl_xor(tsl, 32, 64);

  if constexpr (NKG > 1) {
    // ---- partials: O (row-layout) + l (col-layout, row = l31) ----
    float* op = Op + (size_t)L * 12288;
    #pragma unroll
    for (int p = 0; p < 4; ++p) {
      #pragma unroll
      for (int jj = 0; jj < 4; ++jj) {
        int qrow = w * 32 + 8 * p + 4 * hi + jj;
        op[(size_t)qrow * 96 + l31]      = o[0][4*p+jj];
        op[(size_t)qrow * 96 + 32 + l31] = o[1][4*p+jj];
        op[(size_t)qrow * 96 + 64 + l31] = o[2][4*p+jj];
      }
    }
    if (hi == 0) lp[(size_t)L * 128 + w * 32 + l31] = lcol;
  } else {
    __syncthreads();
    float* bcf = (float*)smem;
    if (hi == 0) bcf[w * 32 + l31] = 1.0f / lcol;
    __syncthreads();
    #pragma unroll
    for (int p = 0; p < 4; ++p) {
      #pragma unroll
      for (int jj = 0; jj < 4; ++jj) {
        int qr = 8 * p + 4 * hi + jj;
        float iv = bcf[w * 32 + qr];
        short* xp = Xb + ((size_t)(n * S_LEN + q0 + w * 32 + qr)) * EMB + h * HDIM + l31;
        xp[0]  = f2bfh(o[0][4*p+jj] * iv);
        xp[32] = f2bfh(o[1][4*p+jj] * iv);
        xp[64] = f2bfh(o[2][4*p+jj] * iv);
      }
    }
  }
}

// ---------- split-K combine: Xb = (sum_kg O) / (sum_kg l), bf16 ----------
__global__ __launch_bounds__(256) void combine_kernel(const float* __restrict__ Op,
                                                      const float* __restrict__ lp,
                                                      short* __restrict__ Xb,
                                                      int nkg) {
  int b = blockIdx.x;
  int h = b & 7, j = b >> 3, n = j >> 5, qt = j & 31;
  int q0 = qt * 128;
  int tid = threadIdx.x;
  #pragma unroll 1
  for (int i = 0; i < 12; ++i) {
    int idx = (i * 256 + tid) * 4;
    int qr = idx / 96, d = idx - qr * 96;
    float ax = 0.f, ay = 0.f, az = 0.f, aw = 0.f, l = 0.f;
    for (int kg = 0; kg < nkg; ++kg) {
      size_t blk = (size_t)(kg * 512 + b);
      float4 v = *(const float4*)(Op + blk * 12288 + idx);
      ax += v.x; ay += v.y; az += v.z; aw += v.w;
      l += lp[blk * 128 + qr];
    }
    float iv = 1.0f / l;
    short4 r;
    r.x = f2bfh(ax * iv); r.y = f2bfh(ay * iv);
    r.z = f2bfh(az * iv); r.w = f2bfh(aw * iv);
    *(short4*)(Xb + ((size_t)(n * S_LEN + q0 + qr)) * EMB + h * HDIM + d) = r;
  }
}

// ---------- FC: out[m][j] = sum_k X[m][k] * W[j][k] + b[j] ----------
__global__ __launch_bounds__(256) void fc_kernel(const short* __restrict__ Xb,
                                                 const short* __restrict__ Wb,
                                                 const float* __restrict__ bias,
                                                 float* __restrict__ out) {
  int m0 = blockIdx.x * 64, j0 = blockIdx.y * 64;
  int tid = threadIdx.x;
  int w = tid >> 6, lane = tid & 63, lr = lane & 15, lg = lane >> 4;
  f32x4 acc[4];
  #pragma unroll
  for (int jt = 0; jt < 4; ++jt) acc[jt] = (f32x4){0.f, 0.f, 0.f, 0.f};
  const short* xp = Xb + (size_t)(m0 + w * 16 + lr) * EMB + 8 * lg;
  const short* wp = Wb + (size_t)(j0 + lr) * EMB + 8 * lg;
  #pragma unroll 1
  for (int kt = 0; kt < 24; ++kt) {
    bf16x8 a = *(const bf16x8*)(xp + kt * 32);
    #pragma unroll
    for (int jt = 0; jt < 4; ++jt) {
      bf16x8 bw = *(const bf16x8*)(wp + (size_t)(jt * 16) * EMB + kt * 32);
      acc[jt] = __builtin_amdgcn_mfma_f32_16x16x32_bf16(a, bw, acc[jt], 0, 0, 0);
    }
  }
  #pragma unroll
  for (int jt = 0; jt < 4; ++jt) {
    float bb = bias[j0 + jt * 16 + lr];
    #pragma unroll
    for (int i = 0; i < 4; ++i)
      out[(size_t)(m0 + w * 16 + 4 * lg + i) * EMB + j0 + jt * 16 + lr] = acc[jt][i] + bb;
  }
}

extern "C" void kernel_launch(void* const* d_in, const int* in_sizes, int n_in,
                              void* d_out, int out_size, void* d_ws, size_t ws_size,
                              hipStream_t stream) {
  (void)in_sizes; (void)n_in; (void)out_size;
  const float* V = (const float*)d_in[0];
  const float* K = (const float*)d_in[1];
  const float* Q = (const float*)d_in[2];
  const float* W = (const float*)d_in[3];
  const float* B = (const float*)d_in[4];
  float* out = (float*)d_out;
  // ws (shorts): KVT[12582912] | Wb[589824] | Xb[6291456] | partials (f32)
  short* KVT = (short*)d_ws;
  short* Wb  = KVT + 12582912;
  short* Xb  = Wb + 589824;
  size_t base_bytes = (size_t)(12582912 + 589824 + 6291456) * 2;
  size_t part_bytes = (size_t)2 * 512 * (12288 + 128) * 4;
  prep_kernel<<<1312, 256, 0, stream>>>(K, W, V, KVT, Wb);
  if (ws_size >= base_bytes + part_bytes) {
    float* Op = (float*)((char*)d_ws + base_bytes);
    float* lp = Op + (size_t)2 * 512 * 12288;
    attn_kernel<2><<<1024, 256, 0, stream>>>(Q, KVT, Xb, Op, lp);
    combine_kernel<<<512, 256, 0, stream>>>(Op, lp, Xb, 2);
  } else {
    attn_kernel<1><<<512, 256, 0, stream>>>(Q, KVT, Xb, nullptr, nullptr);
  }
  fc_kernel<<<dim3(128, 12), 256, 0, stream>>>(Xb, Wb, B, out);
}

// Round 16
// 216.693 us; speedup vs baseline: 1.3873x; 1.0015x over previous
//
#include <hip/hip_runtime.h>
#include <hip/hip_bf16.h>

#define S_LEN 4096
#define EMB 768
#define NHEAD 8
#define HDIM 96

typedef short bf16x8 __attribute__((ext_vector_type(8)));
typedef float f32x4 __attribute__((ext_vector_type(4)));
typedef float f32x16 __attribute__((ext_vector_type(16)));

__device__ __forceinline__ short f2bf(float x) {
  union { float f; unsigned u; } v; v.f = x;
  unsigned r = v.u + 0x7fffu + ((v.u >> 16) & 1u);   // round-to-nearest-even
  return (short)(r >> 16);
}

__device__ __forceinline__ short f2bfh(float x) {
  union { __hip_bfloat16 h; short s; } u;
  u.h = __float2bfloat16(x);
  return u.s;
}

#define GLOAD_LDS16(gp, lp)                                              \
  __builtin_amdgcn_global_load_lds(                                      \
      (const __attribute__((address_space(1))) unsigned int*)(gp),       \
      (__attribute__((address_space(3))) unsigned int*)(lp), 16, 0, 0)

// ---------- fused prep ----------
// blocks [0,288):      W -> bf16.
// blocks [288,1312):   K half of KVT tile (12KB): unit u = c*128 + ksub*64 + hi*32 + l31
//                      holds K[32ksub+l31][16c+8hi .. +7]  -> QK A-frag read is
//                      base + lane*16 (lane-linear, conflict-free).
// blocks [1312,2336):  V half (12KB): r13 lane-linear sigma layout (sigma = swap key
//                      bits 2<->3, matches 32x32 MFMA C/D slots -> P packs identity).
__global__ __launch_bounds__(256) void prep_kernel(const float* __restrict__ K,
                                                   const float* __restrict__ W,
                                                   const float* __restrict__ V,
                                                   short* __restrict__ KVT,
                                                   short* __restrict__ Wb) {
  __shared__ short tlbuf[6656];
  int b = blockIdx.x;
  int tid = threadIdx.x;
  if (b < 288) {
    int t = b * 256 + tid;
    size_t off = (size_t)t * 8;
    float4 a = *(const float4*)(W + off);
    float4 bq = *(const float4*)(W + off + 4);
    bf16x8 r;
    r[0]=f2bf(a.x);  r[1]=f2bf(a.y);  r[2]=f2bf(a.z);  r[3]=f2bf(a.w);
    r[4]=f2bf(bq.x); r[5]=f2bf(bq.y); r[6]=f2bf(bq.z); r[7]=f2bf(bq.w);
    *(bf16x8*)(Wb + off) = r;
    return;
  }
  if (b < 1312) {
    // ---- K tile: (n, h, 64-key tile) ----
    int bb = b - 288;
    int n = bb >> 9, h = (bb >> 6) & 7, st = bb & 63;
    int s0 = st * 64;
    const float* kp = K + ((size_t)(n * S_LEN + s0)) * EMB + h * HDIM;
    #pragma unroll
    for (int k = 0; k < 6; ++k) {
      int idx = k * 256 + tid;
      int fidx = idx * 4;
      int s = fidx / 96, d = fidx % 96;
      float4 a = *(const float4*)(kp + (size_t)s * EMB + d);
      short* t4 = &tlbuf[s * 104 + d];
      t4[0] = f2bf(a.x); t4[1] = f2bf(a.y); t4[2] = f2bf(a.z); t4[3] = f2bf(a.w);
    }
    __syncthreads();
    short* KVp = KVT + ((size_t)((n * NHEAD + h) * 64 + st)) * 12288;
    #pragma unroll
    for (int i = 0; i < 3; ++i) {
      int u = i * 256 + tid;           // K unit 0..767
      int c = u >> 7, rem = u & 127;
      int ksub = (rem >> 6) & 1, hi2 = (rem >> 5) & 1, l31 = rem & 31;
      int key = ksub * 32 + l31;
      int db = c * 16 + hi2 * 8;
      short4 lo = *(const short4*)&tlbuf[key * 104 + db];
      short4 hi4 = *(const short4*)&tlbuf[key * 104 + db + 4];
      bf16x8 r;
      r[0]=lo.x; r[1]=lo.y; r[2]=lo.z; r[3]=lo.w;
      r[4]=hi4.x; r[5]=hi4.y; r[6]=hi4.z; r[7]=hi4.w;
      *(bf16x8*)(KVp + (size_t)u * 8) = r;
    }
    return;
  }
  // ---- V tile ----
  int bb = b - 1312;
  int n = bb >> 9, h = (bb >> 6) & 7, st = bb & 63;
  int s0 = st * 64;
  const float* vp = V + ((size_t)(n * S_LEN + s0)) * EMB + h * HDIM;
  #pragma unroll
  for (int k = 0; k < 6; ++k) {
    int idx = k * 256 + tid;
    int fidx = idx * 4;
    int s = fidx / 96, d = fidx % 96;
    float4 a = *(const float4*)(vp + (size_t)s * EMB + d);
    tlbuf[(d + 0) * 68 + s] = f2bf(a.x);
    tlbuf[(d + 1) * 68 + s] = f2bf(a.y);
    tlbuf[(d + 2) * 68 + s] = f2bf(a.z);
    tlbuf[(d + 3) * 68 + s] = f2bf(a.w);
  }
  __syncthreads();
  short* KVp = KVT + ((size_t)((n * NHEAD + h) * 64 + st)) * 12288 + 6144;
  #pragma unroll
  for (int i = 0; i < 3; ++i) {
    int u = i * 256 + tid;           // V unit 0..767
    int slice = u / 192;
    int rem = u - slice * 192;
    int dt = rem >> 6, hi2 = (rem >> 5) & 1, d5 = rem & 31;
    int d = dt * 32 + d5;
    int kb = 16 * slice + 4 * hi2;
    short4 lo = *(const short4*)&tlbuf[d * 68 + kb];
    short4 hi4 = *(const short4*)&tlbuf[d * 68 + kb + 8];
    bf16x8 r;
    r[0]=lo.x; r[1]=lo.y; r[2]=lo.z; r[3]=lo.w;
    r[4]=hi4.x; r[5]=hi4.y; r[6]=hi4.z; r[7]=hi4.w;
    *(bf16x8*)(KVp + (size_t)u * 8) = r;
  }
}

// ---------- flash attention: K+V in LDS (gload_lds), dual-s, split-K across blocks ----------
// grid = NKG*512; L -> kg = L>>9, bb = L&511, h = bb&7 (XCD map), n, qt. 4 waves x 32 q.
// Per 64-key tile: one fused 24KB KVT stage (6 gload16/wave, zero staging regs).
// ALL LDS reads now lane-linear (K fixed this round) -> conflict-free.
// l in-lane with pairwise-tree accumulate (col-layout). Fixed-max softmax ->
// split-K additive: O = sum O_kg / sum l_kg. __launch_bounds__(256,3): dual-s fits.
template<int NKG>
__global__ __launch_bounds__(256, 3) void attn_kernel(const float* __restrict__ Q,
                                                      const short* __restrict__ KVT,
                                                      short* __restrict__ Xb,
                                                      float* __restrict__ Op,
                                                      float* __restrict__ lp) {
  __shared__ __align__(16) char smem[49152];
  constexpr int ITERS = S_LEN / NKG / 64;
  int L = blockIdx.x;
  int bb = L & 511;
  int kg = L >> 9;
  int h = bb & 7, j = bb >> 3;
  int n = j >> 5, qt = j & 31;
  int q0 = qt * 128;
  int tid = threadIdx.x;
  int w = tid >> 6, lane = tid & 63, l31 = lane & 31, hi = lane >> 5;

  const float kAdj = 0.14724512f;  // (1/sqrt(96)) * log2(e), folded into Q
  bf16x8 qf[6];
  {
    const float* qp = Q + ((size_t)(n * S_LEN + q0 + w * 32 + l31)) * EMB + h * HDIM + 8 * hi;
    #pragma unroll
    for (int c = 0; c < 6; ++c) {
      float4 a = *(const float4*)(qp + 16 * c);
      float4 bq = *(const float4*)(qp + 16 * c + 4);
      bf16x8 r;
      r[0]=f2bf(a.x*kAdj);  r[1]=f2bf(a.y*kAdj);  r[2]=f2bf(a.z*kAdj);  r[3]=f2bf(a.w*kAdj);
      r[4]=f2bf(bq.x*kAdj); r[5]=f2bf(bq.y*kAdj); r[6]=f2bf(bq.z*kAdj); r[7]=f2bf(bq.w*kAdj);
      qf[c] = r;
    }
  }

  const short* gKV = KVT + ((size_t)((n * NHEAD + h) * 64 + kg * ITERS)) * 12288
                        + (size_t)(w * 6) * 512 + lane * 8;
  char* ldsw = smem + w * 6144;

  // prologue: stage tile0 -> buf0
  #pragma unroll
  for (int i = 0; i < 6; ++i)
    GLOAD_LDS16(gKV + i * 512, ldsw + i * 1024);
  __syncthreads();

  f32x16 o[3];
  #pragma unroll
  for (int dt = 0; dt < 3; ++dt) o[dt] = (f32x16){};
  float tsl = 0.f;

  int cur = 0;
  #pragma unroll 1
  for (int t = 0; t < ITERS; ++t) {
    if (t < ITERS - 1) {
      const short* src = gKV + (size_t)(t + 1) * 12288;
      char* dst = ldsw + (cur ^ 1) * 24576;
      #pragma unroll
      for (int i = 0; i < 6; ++i)
        GLOAD_LDS16(src + i * 512, dst + i * 1024);
    }
    const char* kbl = smem + cur * 24576;          // K part (lane-linear)
    const char* vbl = kbl + 12288;                 // V part (lane-linear)

    // ---- QK^T both 32-key subtiles (12 independent ds_read+MFMA) ----
    f32x16 s0 = (f32x16){}, s1 = (f32x16){};
    __builtin_amdgcn_s_setprio(1);
    #pragma unroll
    for (int c = 0; c < 6; ++c) {
      bf16x8 kf = *(const bf16x8*)(kbl + c * 2048 + lane * 16);
      s0 = __builtin_amdgcn_mfma_f32_32x32x16_bf16(kf, qf[c], s0, 0, 0, 0);
    }
    #pragma unroll
    for (int c = 0; c < 6; ++c) {
      bf16x8 kf = *(const bf16x8*)(kbl + c * 2048 + 1024 + lane * 16);
      s1 = __builtin_amdgcn_mfma_f32_32x32x16_bf16(kf, qf[c], s1, 0, 0, 0);
    }
    __builtin_amdgcn_s_setprio(0);

    // ---- P = 2^score; pairwise-tree row-sum (col-layout, breaks serial chain) ----
    #pragma unroll
    for (int r = 0; r < 16; ++r) s0[r] = __builtin_amdgcn_exp2f(s0[r]);
    #pragma unroll
    for (int r = 0; r < 16; ++r) s1[r] = __builtin_amdgcn_exp2f(s1[r]);
    {
      float a0 = (s0[0]+s0[1]) + (s0[2]+s0[3]), a1 = (s0[4]+s0[5]) + (s0[6]+s0[7]);
      float a2 = (s0[8]+s0[9]) + (s0[10]+s0[11]), a3 = (s0[12]+s0[13]) + (s0[14]+s0[15]);
      float b0 = (s1[0]+s1[1]) + (s1[2]+s1[3]), b1 = (s1[4]+s1[5]) + (s1[6]+s1[7]);
      float b2 = (s1[8]+s1[9]) + (s1[10]+s1[11]), b3 = (s1[12]+s1[13]) + (s1[14]+s1[15]);
      tsl += ((a0+a1) + (a2+a3)) + ((b0+b1) + (b2+b3));
    }

    // ---- pack (identity) + PV per 16-key slice ----
    #pragma unroll
    for (int ksub = 0; ksub < 2; ++ksub) {
      const f32x16& s = ksub ? s1 : s0;
      #pragma unroll
      for (int ks = 0; ks < 2; ++ks) {
        unsigned d0, d1, d2, d3;
        asm("v_cvt_pk_bf16_f32 %0, %1, %2" : "=v"(d0) : "v"(s[8*ks+0]), "v"(s[8*ks+1]));
        asm("v_cvt_pk_bf16_f32 %0, %1, %2" : "=v"(d1) : "v"(s[8*ks+2]), "v"(s[8*ks+3]));
        asm("v_cvt_pk_bf16_f32 %0, %1, %2" : "=v"(d2) : "v"(s[8*ks+4]), "v"(s[8*ks+5]));
        asm("v_cvt_pk_bf16_f32 %0, %1, %2" : "=v"(d3) : "v"(s[8*ks+6]), "v"(s[8*ks+7]));
        union { unsigned u[4]; bf16x8 v; } pu;
        pu.u[0] = d0; pu.u[1] = d1; pu.u[2] = d2; pu.u[3] = d3;
        int slice = 2 * ksub + ks;
        __builtin_amdgcn_s_setprio(1);
        #pragma unroll
        for (int dt = 0; dt < 3; ++dt) {
          bf16x8 vf = *(const bf16x8*)(vbl + (slice * 3 + dt) * 1024 + hi * 512 + l31 * 16);
          o[dt] = __builtin_amdgcn_mfma_f32_32x32x16_bf16(pu.v, vf, o[dt], 0, 0, 0);
        }
        __builtin_amdgcn_s_setprio(0);
      }
    }
    __syncthreads();     // staging drained (issued before compute); buffers swap
    cur ^= 1;
  }

  float lcol = tsl + __shfl_xor(tsl, 32, 64);

  if constexpr (NKG > 1) {
    // ---- partials: O (row-layout) + l (col-layout, row = l31) ----
    float* op = Op + (size_t)L * 12288;
    #pragma unroll
    for (int p = 0; p < 4; ++p) {
      #pragma unroll
      for (int jj = 0; jj < 4; ++jj) {
        int qrow = w * 32 + 8 * p + 4 * hi + jj;
        op[(size_t)qrow * 96 + l31]      = o[0][4*p+jj];
        op[(size_t)qrow * 96 + 32 + l31] = o[1][4*p+jj];
        op[(size_t)qrow * 96 + 64 + l31] = o[2][4*p+jj];
      }
    }
    if (hi == 0) lp[(size_t)L * 128 + w * 32 + l31] = lcol;
  } else {
    __syncthreads();
    float* bcf = (float*)smem;
    if (hi == 0) bcf[w * 32 + l31] = 1.0f / lcol;
    __syncthreads();
    #pragma unroll
    for (int p = 0; p < 4; ++p) {
      #pragma unroll
      for (int jj = 0; jj < 4; ++jj) {
        int qr = 8 * p + 4 * hi + jj;
        float iv = bcf[w * 32 + qr];
        short* xp = Xb + ((size_t)(n * S_LEN + q0 + w * 32 + qr)) * EMB + h * HDIM + l31;
        xp[0]  = f2bfh(o[0][4*p+jj] * iv);
        xp[32] = f2bfh(o[1][4*p+jj] * iv);
        xp[64] = f2bfh(o[2][4*p+jj] * iv);
      }
    }
  }
}

// ---------- split-K combine: Xb = (sum_kg O) / (sum_kg l), bf16 ----------
__global__ __launch_bounds__(256) void combine_kernel(const float* __restrict__ Op,
                                                      const float* __restrict__ lp,
                                                      short* __restrict__ Xb,
                                                      int nkg) {
  int b = blockIdx.x;
  int h = b & 7, j = b >> 3, n = j >> 5, qt = j & 31;
  int q0 = qt * 128;
  int tid = threadIdx.x;
  #pragma unroll 1
  for (int i = 0; i < 12; ++i) {
    int idx = (i * 256 + tid) * 4;
    int qr = idx / 96, d = idx - qr * 96;
    float ax = 0.f, ay = 0.f, az = 0.f, aw = 0.f, l = 0.f;
    for (int kg = 0; kg < nkg; ++kg) {
      size_t blk = (size_t)(kg * 512 + b);
      float4 v = *(const float4*)(Op + blk * 12288 + idx);
      ax += v.x; ay += v.y; az += v.z; aw += v.w;
      l += lp[blk * 128 + qr];
    }
    float iv = 1.0f / l;
    short4 r;
    r.x = f2bfh(ax * iv); r.y = f2bfh(ay * iv);
    r.z = f2bfh(az * iv); r.w = f2bfh(aw * iv);
    *(short4*)(Xb + ((size_t)(n * S_LEN + q0 + qr)) * EMB + h * HDIM + d) = r;
  }
}

// ---------- FC: out[m][j] = sum_k X[m][k] * W[j][k] + b[j] ----------
__global__ __launch_bounds__(256) void fc_kernel(const short* __restrict__ Xb,
                                                 const short* __restrict__ Wb,
                                                 const float* __restrict__ bias,
                                                 float* __restrict__ out) {
  int m0 = blockIdx.x * 64, j0 = blockIdx.y * 64;
  int tid = threadIdx.x;
  int w = tid >> 6, lane = tid & 63, lr = lane & 15, lg = lane >> 4;
  f32x4 acc[4];
  #pragma unroll
  for (int jt = 0; jt < 4; ++jt) acc[jt] = (f32x4){0.f, 0.f, 0.f, 0.f};
  const short* xp = Xb + (size_t)(m0 + w * 16 + lr) * EMB + 8 * lg;
  const short* wp = Wb + (size_t)(j0 + lr) * EMB + 8 * lg;
  #pragma unroll 1
  for (int kt = 0; kt < 24; ++kt) {
    bf16x8 a = *(const bf16x8*)(xp + kt * 32);
    #pragma unroll
    for (int jt = 0; jt < 4; ++jt) {
      bf16x8 bw = *(const bf16x8*)(wp + (size_t)(jt * 16) * EMB + kt * 32);
      acc[jt] = __builtin_amdgcn_mfma_f32_16x16x32_bf16(a, bw, acc[jt], 0, 0, 0);
    }
  }
  #pragma unroll
  for (int jt = 0; jt < 4; ++jt) {
    float bb = bias[j0 + jt * 16 + lr];
    #pragma unroll
    for (int i = 0; i < 4; ++i)
      out[(size_t)(m0 + w * 16 + 4 * lg + i) * EMB + j0 + jt * 16 + lr] = acc[jt][i] + bb;
  }
}

extern "C" void kernel_launch(void* const* d_in, const int* in_sizes, int n_in,
                              void* d_out, int out_size, void* d_ws, size_t ws_size,
                              hipStream_t stream) {
  (void)in_sizes; (void)n_in; (void)out_size;
  const float* V = (const float*)d_in[0];
  const float* K = (const float*)d_in[1];
  const float* Q = (const float*)d_in[2];
  const float* W = (const float*)d_in[3];
  const float* B = (const float*)d_in[4];
  float* out = (float*)d_out;
  // ws (shorts): KVT[12582912] | Wb[589824] | Xb[6291456] | partials (f32)
  short* KVT = (short*)d_ws;
  short* Wb  = KVT + 12582912;
  short* Xb  = Wb + 589824;
  size_t base_bytes = (size_t)(12582912 + 589824 + 6291456) * 2;
  size_t part_bytes = (size_t)2 * 512 * (12288 + 128) * 4;
  prep_kernel<<<2336, 256, 0, stream>>>(K, W, V, KVT, Wb);
  if (ws_size >= base_bytes + part_bytes) {
    float* Op = (float*)((char*)d_ws + base_bytes);
    float* lp = Op + (size_t)2 * 512 * 12288;
    attn_kernel<2><<<1024, 256, 0, stream>>>(Q, KVT, Xb, Op, lp);
    combine_kernel<<<512, 256, 0, stream>>>(Op, lp, Xb, 2);
  } else {
    attn_kernel<1><<<512, 256, 0, stream>>>(Q, KVT, Xb, nullptr, nullptr);
  }
  fc_kernel<<<dim3(128, 12), 256, 0, stream>>>(Xb, Wb, B, out);
}

// Round 17
// 214.864 us; speedup vs baseline: 1.3991x; 1.0085x over previous
//
#include <hip/hip_runtime.h>
#include <hip/hip_bf16.h>

#define S_LEN 4096
#define EMB 768
#define NHEAD 8
#define HDIM 96

typedef short bf16x8 __attribute__((ext_vector_type(8)));
typedef float f32x4 __attribute__((ext_vector_type(4)));
typedef float f32x16 __attribute__((ext_vector_type(16)));

__device__ __forceinline__ short f2bf(float x) {
  union { float f; unsigned u; } v; v.f = x;
  unsigned r = v.u + 0x7fffu + ((v.u >> 16) & 1u);   // round-to-nearest-even
  return (short)(r >> 16);
}

__device__ __forceinline__ short f2bfh(float x) {
  union { __hip_bfloat16 h; short s; } u;
  u.h = __float2bfloat16(x);
  return u.s;
}

#define GLOAD_LDS16(gp, lp)                                              \
  __builtin_amdgcn_global_load_lds(                                      \
      (const __attribute__((address_space(1))) unsigned int*)(gp),       \
      (__attribute__((address_space(3))) unsigned int*)(lp), 16, 0, 0)

// ---------- fused prep (unchanged from r16) ----------
// blocks [0,288):      W -> bf16.
// blocks [288,1312):   K half of KVT tile (12KB): unit u = c*128 + ksub*64 + hi*32 + l31
//                      holds K[32ksub+l31][16c+8hi .. +7]  -> QK A-frag read is
//                      base + lane*16 (lane-linear, conflict-free).
// blocks [1312,2336):  V half (12KB): lane-linear sigma layout (sigma = swap key
//                      bits 2<->3, matches 32x32 MFMA C/D slots -> P packs identity).
__global__ __launch_bounds__(256) void prep_kernel(const float* __restrict__ K,
                                                   const float* __restrict__ W,
                                                   const float* __restrict__ V,
                                                   short* __restrict__ KVT,
                                                   short* __restrict__ Wb) {
  __shared__ short tlbuf[6656];
  int b = blockIdx.x;
  int tid = threadIdx.x;
  if (b < 288) {
    int t = b * 256 + tid;
    size_t off = (size_t)t * 8;
    float4 a = *(const float4*)(W + off);
    float4 bq = *(const float4*)(W + off + 4);
    bf16x8 r;
    r[0]=f2bf(a.x);  r[1]=f2bf(a.y);  r[2]=f2bf(a.z);  r[3]=f2bf(a.w);
    r[4]=f2bf(bq.x); r[5]=f2bf(bq.y); r[6]=f2bf(bq.z); r[7]=f2bf(bq.w);
    *(bf16x8*)(Wb + off) = r;
    return;
  }
  if (b < 1312) {
    // ---- K tile: (n, h, 64-key tile) ----
    int bb = b - 288;
    int n = bb >> 9, h = (bb >> 6) & 7, st = bb & 63;
    int s0 = st * 64;
    const float* kp = K + ((size_t)(n * S_LEN + s0)) * EMB + h * HDIM;
    #pragma unroll
    for (int k = 0; k < 6; ++k) {
      int idx = k * 256 + tid;
      int fidx = idx * 4;
      int s = fidx / 96, d = fidx % 96;
      float4 a = *(const float4*)(kp + (size_t)s * EMB + d);
      short* t4 = &tlbuf[s * 104 + d];
      t4[0] = f2bf(a.x); t4[1] = f2bf(a.y); t4[2] = f2bf(a.z); t4[3] = f2bf(a.w);
    }
    __syncthreads();
    short* KVp = KVT + ((size_t)((n * NHEAD + h) * 64 + st)) * 12288;
    #pragma unroll
    for (int i = 0; i < 3; ++i) {
      int u = i * 256 + tid;           // K unit 0..767
      int c = u >> 7, rem = u & 127;
      int ksub = (rem >> 6) & 1, hi2 = (rem >> 5) & 1, l31 = rem & 31;
      int key = ksub * 32 + l31;
      int db = c * 16 + hi2 * 8;
      short4 lo = *(const short4*)&tlbuf[key * 104 + db];
      short4 hi4 = *(const short4*)&tlbuf[key * 104 + db + 4];
      bf16x8 r;
      r[0]=lo.x; r[1]=lo.y; r[2]=lo.z; r[3]=lo.w;
      r[4]=hi4.x; r[5]=hi4.y; r[6]=hi4.z; r[7]=hi4.w;
      *(bf16x8*)(KVp + (size_t)u * 8) = r;
    }
    return;
  }
  // ---- V tile ----
  int bb = b - 1312;
  int n = bb >> 9, h = (bb >> 6) & 7, st = bb & 63;
  int s0 = st * 64;
  const float* vp = V + ((size_t)(n * S_LEN + s0)) * EMB + h * HDIM;
  #pragma unroll
  for (int k = 0; k < 6; ++k) {
    int idx = k * 256 + tid;
    int fidx = idx * 4;
    int s = fidx / 96, d = fidx % 96;
    float4 a = *(const float4*)(vp + (size_t)s * EMB + d);
    tlbuf[(d + 0) * 68 + s] = f2bf(a.x);
    tlbuf[(d + 1) * 68 + s] = f2bf(a.y);
    tlbuf[(d + 2) * 68 + s] = f2bf(a.z);
    tlbuf[(d + 3) * 68 + s] = f2bf(a.w);
  }
  __syncthreads();
  short* KVp = KVT + ((size_t)((n * NHEAD + h) * 64 + st)) * 12288 + 6144;
  #pragma unroll
  for (int i = 0; i < 3; ++i) {
    int u = i * 256 + tid;           // V unit 0..767
    int slice = u / 192;
    int rem = u - slice * 192;
    int dt = rem >> 6, hi2 = (rem >> 5) & 1, d5 = rem & 31;
    int d = dt * 32 + d5;
    int kb = 16 * slice + 4 * hi2;
    short4 lo = *(const short4*)&tlbuf[d * 68 + kb];
    short4 hi4 = *(const short4*)&tlbuf[d * 68 + kb + 8];
    bf16x8 r;
    r[0]=lo.x; r[1]=lo.y; r[2]=lo.z; r[3]=lo.w;
    r[4]=hi4.x; r[5]=hi4.y; r[6]=hi4.z; r[7]=hi4.w;
    *(bf16x8*)(KVp + (size_t)u * 8) = r;
  }
}

// ---------- flash attention: K single-buffer + V double-buffer -> 36KB LDS, 4 blocks/CU ----------
// grid = NKG*512 all co-resident (1024 blocks / 256 CU = 4/CU at 36KB; no scheduling tail,
// which cost ~25us at 48KB/3-per-CU). 4 waves x 32 q; dual-s QK (12 independent MFMA).
// Iter structure: QK(kbuf) | barrier1 (cheap: nothing to drain) | issue K(t+1)->kbuf +
// V(t+1)->vbuf^1 via global_load_lds | exp/pack/PV(vbuf[cur]) | barrier2 (drains staging,
// hidden under softmax+PV). K(t) reads all complete at barrier1, so overwrite is safe.
// All LDS reads lane-linear (conflict-free, r16-verified). Fixed-max softmax ->
// split-K additive: O = sum O_kg / sum l_kg. Regs ~116 total <= 128 cap of (256,4).
template<int NKG>
__global__ __launch_bounds__(256, 4) void attn_kernel(const float* __restrict__ Q,
                                                      const short* __restrict__ KVT,
                                                      short* __restrict__ Xb,
                                                      float* __restrict__ Op,
                                                      float* __restrict__ lp) {
  __shared__ __align__(16) char smem[36864];   // kbuf 12KB @0 | vbuf[2] 12KB @12288
  constexpr int ITERS = S_LEN / NKG / 64;
  int L = blockIdx.x;
  int bb = L & 511;
  int kg = L >> 9;
  int h = bb & 7, j = bb >> 3;
  int n = j >> 5, qt = j & 31;
  int q0 = qt * 128;
  int tid = threadIdx.x;
  int w = tid >> 6, lane = tid & 63, l31 = lane & 31, hi = lane >> 5;

  const float kAdj = 0.14724512f;  // (1/sqrt(96)) * log2(e), folded into Q
  bf16x8 qf[6];
  {
    const float* qp = Q + ((size_t)(n * S_LEN + q0 + w * 32 + l31)) * EMB + h * HDIM + 8 * hi;
    #pragma unroll
    for (int c = 0; c < 6; ++c) {
      float4 a = *(const float4*)(qp + 16 * c);
      float4 bq = *(const float4*)(qp + 16 * c + 4);
      bf16x8 r;
      r[0]=f2bf(a.x*kAdj);  r[1]=f2bf(a.y*kAdj);  r[2]=f2bf(a.z*kAdj);  r[3]=f2bf(a.w*kAdj);
      r[4]=f2bf(bq.x*kAdj); r[5]=f2bf(bq.y*kAdj); r[6]=f2bf(bq.z*kAdj); r[7]=f2bf(bq.w*kAdj);
      qf[c] = r;
    }
  }

  // per-wave staging shares: K units w*3..w*3+2 (of 12), V units w*3..w*3+2 (of 12)
  const short* gKV = KVT + ((size_t)((n * NHEAD + h) * 64 + kg * ITERS)) * 12288
                        + (size_t)(w * 3) * 512 + lane * 8;   // K src base
  char* kbuf = smem;
  char* vbuf = smem + 12288;
  char* kdst = kbuf + w * 3072;
  char* vdst0 = vbuf + w * 3072;

  // prologue: stage K(0) + V(0) -> kbuf, vbuf[0]
  #pragma unroll
  for (int i = 0; i < 3; ++i) {
    GLOAD_LDS16(gKV + i * 512, kdst + i * 1024);
    GLOAD_LDS16(gKV + 6144 + i * 512, vdst0 + i * 1024);
  }
  __syncthreads();

  f32x16 o[3];
  #pragma unroll
  for (int dt = 0; dt < 3; ++dt) o[dt] = (f32x16){};
  float tsl = 0.f;

  int cur = 0;
  #pragma unroll 1
  for (int t = 0; t < ITERS; ++t) {
    // ---- QK^T both 32-key subtiles (12 independent ds_read+MFMA) ----
    f32x16 s0 = (f32x16){}, s1 = (f32x16){};
    __builtin_amdgcn_s_setprio(1);
    #pragma unroll
    for (int c = 0; c < 6; ++c) {
      bf16x8 kf = *(const bf16x8*)(kbuf + c * 2048 + lane * 16);
      s0 = __builtin_amdgcn_mfma_f32_32x32x16_bf16(kf, qf[c], s0, 0, 0, 0);
    }
    #pragma unroll
    for (int c = 0; c < 6; ++c) {
      bf16x8 kf = *(const bf16x8*)(kbuf + c * 2048 + 1024 + lane * 16);
      s1 = __builtin_amdgcn_mfma_f32_32x32x16_bf16(kf, qf[c], s1, 0, 0, 0);
    }
    __builtin_amdgcn_s_setprio(0);
    __syncthreads();               // all waves done reading K(t); nothing to drain

    if (t < ITERS - 1) {           // stage K(t+1) -> kbuf, V(t+1) -> vbuf^1
      const short* src = gKV + (size_t)(t + 1) * 12288;
      char* vd = vbuf + (cur ^ 1) * 12288 + w * 3072;
      #pragma unroll
      for (int i = 0; i < 3; ++i) {
        GLOAD_LDS16(src + i * 512, kdst + i * 1024);
        GLOAD_LDS16(src + 6144 + i * 512, vd + i * 1024);
      }
    }

    // ---- P = 2^score; pairwise-tree row-sum (col-layout) ----
    #pragma unroll
    for (int r = 0; r < 16; ++r) s0[r] = __builtin_amdgcn_exp2f(s0[r]);
    #pragma unroll
    for (int r = 0; r < 16; ++r) s1[r] = __builtin_amdgcn_exp2f(s1[r]);
    {
      float a0 = (s0[0]+s0[1]) + (s0[2]+s0[3]), a1 = (s0[4]+s0[5]) + (s0[6]+s0[7]);
      float a2 = (s0[8]+s0[9]) + (s0[10]+s0[11]), a3 = (s0[12]+s0[13]) + (s0[14]+s0[15]);
      float b0 = (s1[0]+s1[1]) + (s1[2]+s1[3]), b1 = (s1[4]+s1[5]) + (s1[6]+s1[7]);
      float b2 = (s1[8]+s1[9]) + (s1[10]+s1[11]), b3 = (s1[12]+s1[13]) + (s1[14]+s1[15]);
      tsl += ((a0+a1) + (a2+a3)) + ((b0+b1) + (b2+b3));
    }

    // ---- pack (identity) + PV per 16-key slice; V(t) from vbuf[cur] ----
    const char* vbl = vbuf + cur * 12288;
    #pragma unroll
    for (int ksub = 0; ksub < 2; ++ksub) {
      const f32x16& s = ksub ? s1 : s0;
      #pragma unroll
      for (int ks = 0; ks < 2; ++ks) {
        unsigned d0, d1, d2, d3;
        asm("v_cvt_pk_bf16_f32 %0, %1, %2" : "=v"(d0) : "v"(s[8*ks+0]), "v"(s[8*ks+1]));
        asm("v_cvt_pk_bf16_f32 %0, %1, %2" : "=v"(d1) : "v"(s[8*ks+2]), "v"(s[8*ks+3]));
        asm("v_cvt_pk_bf16_f32 %0, %1, %2" : "=v"(d2) : "v"(s[8*ks+4]), "v"(s[8*ks+5]));
        asm("v_cvt_pk_bf16_f32 %0, %1, %2" : "=v"(d3) : "v"(s[8*ks+6]), "v"(s[8*ks+7]));
        union { unsigned u[4]; bf16x8 v; } pu;
        pu.u[0] = d0; pu.u[1] = d1; pu.u[2] = d2; pu.u[3] = d3;
        int slice = 2 * ksub + ks;
        __builtin_amdgcn_s_setprio(1);
        #pragma unroll
        for (int dt = 0; dt < 3; ++dt) {
          bf16x8 vf = *(const bf16x8*)(vbl + (slice * 3 + dt) * 1024 + hi * 512 + l31 * 16);
          o[dt] = __builtin_amdgcn_mfma_f32_32x32x16_bf16(pu.v, vf, o[dt], 0, 0, 0);
        }
        __builtin_amdgcn_s_setprio(0);
      }
    }
    __syncthreads();     // drains K(t+1)/V(t+1) staging (hidden under softmax+PV)
    cur ^= 1;
  }

  float lcol = tsl + __shfl_xor(tsl, 32, 64);

  if constexpr (NKG > 1) {
    // ---- partials: O (row-layout) + l (col-layout, row = l31) ----
    float* op = Op + (size_t)L * 12288;
    #pragma unroll
    for (int p = 0; p < 4; ++p) {
      #pragma unroll
      for (int jj = 0; jj < 4; ++jj) {
        int qrow = w * 32 + 8 * p + 4 * hi + jj;
        op[(size_t)qrow * 96 + l31]      = o[0][4*p+jj];
        op[(size_t)qrow * 96 + 32 + l31] = o[1][4*p+jj];
        op[(size_t)qrow * 96 + 64 + l31] = o[2][4*p+jj];
      }
    }
    if (hi == 0) lp[(size_t)L * 128 + w * 32 + l31] = lcol;
  } else {
    __syncthreads();
    float* bcf = (float*)smem;
    if (hi == 0) bcf[w * 32 + l31] = 1.0f / lcol;
    __syncthreads();
    #pragma unroll
    for (int p = 0; p < 4; ++p) {
      #pragma unroll
      for (int jj = 0; jj < 4; ++jj) {
        int qr = 8 * p + 4 * hi + jj;
        float iv = bcf[w * 32 + qr];
        short* xp = Xb + ((size_t)(n * S_LEN + q0 + w * 32 + qr)) * EMB + h * HDIM + l31;
        xp[0]  = f2bfh(o[0][4*p+jj] * iv);
        xp[32] = f2bfh(o[1][4*p+jj] * iv);
        xp[64] = f2bfh(o[2][4*p+jj] * iv);
      }
    }
  }
}

// ---------- split-K combine: Xb = (sum_kg O) / (sum_kg l), bf16 ----------
__global__ __launch_bounds__(256) void combine_kernel(const float* __restrict__ Op,
                                                      const float* __restrict__ lp,
                                                      short* __restrict__ Xb,
                                                      int nkg) {
  int b = blockIdx.x;
  int h = b & 7, j = b >> 3, n = j >> 5, qt = j & 31;
  int q0 = qt * 128;
  int tid = threadIdx.x;
  #pragma unroll 1
  for (int i = 0; i < 12; ++i) {
    int idx = (i * 256 + tid) * 4;
    int qr = idx / 96, d = idx - qr * 96;
    float ax = 0.f, ay = 0.f, az = 0.f, aw = 0.f, l = 0.f;
    for (int kg = 0; kg < nkg; ++kg) {
      size_t blk = (size_t)(kg * 512 + b);
      float4 v = *(const float4*)(Op + blk * 12288 + idx);
      ax += v.x; ay += v.y; az += v.z; aw += v.w;
      l += lp[blk * 128 + qr];
    }
    float iv = 1.0f / l;
    short4 r;
    r.x = f2bfh(ax * iv); r.y = f2bfh(ay * iv);
    r.z = f2bfh(az * iv); r.w = f2bfh(aw * iv);
    *(short4*)(Xb + ((size_t)(n * S_LEN + q0 + qr)) * EMB + h * HDIM + d) = r;
  }
}

// ---------- FC: out[m][j] = sum_k X[m][k] * W[j][k] + b[j] ----------
__global__ __launch_bounds__(256) void fc_kernel(const short* __restrict__ Xb,
                                                 const short* __restrict__ Wb,
                                                 const float* __restrict__ bias,
                                                 float* __restrict__ out) {
  int m0 = blockIdx.x * 64, j0 = blockIdx.y * 64;
  int tid = threadIdx.x;
  int w = tid >> 6, lane = tid & 63, lr = lane & 15, lg = lane >> 4;
  f32x4 acc[4];
  #pragma unroll
  for (int jt = 0; jt < 4; ++jt) acc[jt] = (f32x4){0.f, 0.f, 0.f, 0.f};
  const short* xp = Xb + (size_t)(m0 + w * 16 + lr) * EMB + 8 * lg;
  const short* wp = Wb + (size_t)(j0 + lr) * EMB + 8 * lg;
  #pragma unroll 1
  for (int kt = 0; kt < 24; ++kt) {
    bf16x8 a = *(const bf16x8*)(xp + kt * 32);
    #pragma unroll
    for (int jt = 0; jt < 4; ++jt) {
      bf16x8 bw = *(const bf16x8*)(wp + (size_t)(jt * 16) * EMB + kt * 32);
      acc[jt] = __builtin_amdgcn_mfma_f32_16x16x32_bf16(a, bw, acc[jt], 0, 0, 0);
    }
  }
  #pragma unroll
  for (int jt = 0; jt < 4; ++jt) {
    float bb = bias[j0 + jt * 16 + lr];
    #pragma unroll
    for (int i = 0; i < 4; ++i)
      out[(size_t)(m0 + w * 16 + 4 * lg + i) * EMB + j0 + jt * 16 + lr] = acc[jt][i] + bb;
  }
}

extern "C" void kernel_launch(void* const* d_in, const int* in_sizes, int n_in,
                              void* d_out, int out_size, void* d_ws, size_t ws_size,
                              hipStream_t stream) {
  (void)in_sizes; (void)n_in; (void)out_size;
  const float* V = (const float*)d_in[0];
  const float* K = (const float*)d_in[1];
  const float* Q = (const float*)d_in[2];
  const float* W = (const float*)d_in[3];
  const float* B = (const float*)d_in[4];
  float* out = (float*)d_out;
  // ws (shorts): KVT[12582912] | Wb[589824] | Xb[6291456] | partials (f32)
  short* KVT = (short*)d_ws;
  short* Wb  = KVT + 12582912;
  short* Xb  = Wb + 589824;
  size_t base_bytes = (size_t)(12582912 + 589824 + 6291456) * 2;
  size_t part_bytes = (size_t)2 * 512 * (12288 + 128) * 4;
  prep_kernel<<<2336, 256, 0, stream>>>(K, W, V, KVT, Wb);
  if (ws_size >= base_bytes + part_bytes) {
    float* Op = (float*)((char*)d_ws + base_bytes);
    float* lp = Op + (size_t)2 * 512 * 12288;
    attn_kernel<2><<<1024, 256, 0, stream>>>(Q, KVT, Xb, Op, lp);
    combine_kernel<<<512, 256, 0, stream>>>(Op, lp, Xb, 2);
  } else {
    attn_kernel<1><<<512, 256, 0, stream>>>(Q, KVT, Xb, nullptr, nullptr);
  }
  fc_kernel<<<dim3(128, 12), 256, 0, stream>>>(Xb, Wb, B, out);
}

// Round 18
// 213.804 us; speedup vs baseline: 1.4060x; 1.0050x over previous
//
#include <hip/hip_runtime.h>
#include <hip/hip_bf16.h>

#define S_LEN 4096
#define EMB 768
#define NHEAD 8
#define HDIM 96

typedef short bf16x8 __attribute__((ext_vector_type(8)));
typedef float f32x4 __attribute__((ext_vector_type(4)));
typedef float f32x16 __attribute__((ext_vector_type(16)));

__device__ __forceinline__ short f2bf(float x) {
  union { float f; unsigned u; } v; v.f = x;
  unsigned r = v.u + 0x7fffu + ((v.u >> 16) & 1u);   // round-to-nearest-even
  return (short)(r >> 16);
}

__device__ __forceinline__ short f2bfh(float x) {
  union { __hip_bfloat16 h; short s; } u;
  u.h = __float2bfloat16(x);
  return u.s;
}

#define GLOAD_LDS16(gp, lp)                                              \
  __builtin_amdgcn_global_load_lds(                                      \
      (const __attribute__((address_space(1))) unsigned int*)(gp),       \
      (__attribute__((address_space(3))) unsigned int*)(lp), 16, 0, 0)

// ---------- fused prep (unchanged from r16/r17) ----------
__global__ __launch_bounds__(256) void prep_kernel(const float* __restrict__ K,
                                                   const float* __restrict__ W,
                                                   const float* __restrict__ V,
                                                   short* __restrict__ KVT,
                                                   short* __restrict__ Wb) {
  __shared__ short tlbuf[6656];
  int b = blockIdx.x;
  int tid = threadIdx.x;
  if (b < 288) {
    int t = b * 256 + tid;
    size_t off = (size_t)t * 8;
    float4 a = *(const float4*)(W + off);
    float4 bq = *(const float4*)(W + off + 4);
    bf16x8 r;
    r[0]=f2bf(a.x);  r[1]=f2bf(a.y);  r[2]=f2bf(a.z);  r[3]=f2bf(a.w);
    r[4]=f2bf(bq.x); r[5]=f2bf(bq.y); r[6]=f2bf(bq.z); r[7]=f2bf(bq.w);
    *(bf16x8*)(Wb + off) = r;
    return;
  }
  if (b < 1312) {
    // ---- K tile: unit u = c*128 + ksub*64 + hi*32 + l31 <- K[32ksub+l31][16c+8hi..+7] ----
    int bb = b - 288;
    int n = bb >> 9, h = (bb >> 6) & 7, st = bb & 63;
    int s0 = st * 64;
    const float* kp = K + ((size_t)(n * S_LEN + s0)) * EMB + h * HDIM;
    #pragma unroll
    for (int k = 0; k < 6; ++k) {
      int idx = k * 256 + tid;
      int fidx = idx * 4;
      int s = fidx / 96, d = fidx % 96;
      float4 a = *(const float4*)(kp + (size_t)s * EMB + d);
      short* t4 = &tlbuf[s * 104 + d];
      t4[0] = f2bf(a.x); t4[1] = f2bf(a.y); t4[2] = f2bf(a.z); t4[3] = f2bf(a.w);
    }
    __syncthreads();
    short* KVp = KVT + ((size_t)((n * NHEAD + h) * 64 + st)) * 12288;
    #pragma unroll
    for (int i = 0; i < 3; ++i) {
      int u = i * 256 + tid;
      int c = u >> 7, rem = u & 127;
      int ksub = (rem >> 6) & 1, hi2 = (rem >> 5) & 1, l31 = rem & 31;
      int key = ksub * 32 + l31;
      int db = c * 16 + hi2 * 8;
      short4 lo = *(const short4*)&tlbuf[key * 104 + db];
      short4 hi4 = *(const short4*)&tlbuf[key * 104 + db + 4];
      bf16x8 r;
      r[0]=lo.x; r[1]=lo.y; r[2]=lo.z; r[3]=lo.w;
      r[4]=hi4.x; r[5]=hi4.y; r[6]=hi4.z; r[7]=hi4.w;
      *(bf16x8*)(KVp + (size_t)u * 8) = r;
    }
    return;
  }
  // ---- V tile: lane-linear sigma layout (sigma = swap key bits 2<->3) ----
  int bb = b - 1312;
  int n = bb >> 9, h = (bb >> 6) & 7, st = bb & 63;
  int s0 = st * 64;
  const float* vp = V + ((size_t)(n * S_LEN + s0)) * EMB + h * HDIM;
  #pragma unroll
  for (int k = 0; k < 6; ++k) {
    int idx = k * 256 + tid;
    int fidx = idx * 4;
    int s = fidx / 96, d = fidx % 96;
    float4 a = *(const float4*)(vp + (size_t)s * EMB + d);
    tlbuf[(d + 0) * 68 + s] = f2bf(a.x);
    tlbuf[(d + 1) * 68 + s] = f2bf(a.y);
    tlbuf[(d + 2) * 68 + s] = f2bf(a.z);
    tlbuf[(d + 3) * 68 + s] = f2bf(a.w);
  }
  __syncthreads();
  short* KVp = KVT + ((size_t)((n * NHEAD + h) * 64 + st)) * 12288 + 6144;
  #pragma unroll
  for (int i = 0; i < 3; ++i) {
    int u = i * 256 + tid;
    int slice = u / 192;
    int rem = u - slice * 192;
    int dt = rem >> 6, hi2 = (rem >> 5) & 1, d5 = rem & 31;
    int d = dt * 32 + d5;
    int kb = 16 * slice + 4 * hi2;
    short4 lo = *(const short4*)&tlbuf[d * 68 + kb];
    short4 hi4 = *(const short4*)&tlbuf[d * 68 + kb + 8];
    bf16x8 r;
    r[0]=lo.x; r[1]=lo.y; r[2]=lo.z; r[3]=lo.w;
    r[4]=hi4.x; r[5]=hi4.y; r[6]=hi4.z; r[7]=hi4.w;
    *(bf16x8*)(KVp + (size_t)u * 8) = r;
  }
}

// ---------- flash attention: 64 q-rows/wave register tiling (halves LDS amplification) ----------
// Block = 128 thr = 2 waves x 64 q-rows (q-tile 128); grid = NKG*512, 36KB LDS ->
// 4 blocks/CU all co-resident. r17 diagnosis: LDS read BW was the binding pipe
// (16 waves x 24KB shared-tile re-reads = 384KB/CU-iter ~ 4500cyc). Each K/V fragment
// now feeds TWO q-subtiles (qa: rows +l31, qb: rows +32+l31) -> LDS reads halve to
// 192KB/CU-iter; per-wave ILP doubles (4 indep QK chains) compensating 2 waves/SIMD.
// Iter: QK(kbuf) | barrier1 | stage K(t+1)->kbuf,V(t+1)->vbuf^1 | exp/pack/PV(vbuf[cur])
// | barrier2 (drains staging under softmax+PV). Fixed-max softmax -> split-K additive.
template<int NKG>
__global__ __launch_bounds__(128, 2) void attn_kernel(const float* __restrict__ Q,
                                                      const short* __restrict__ KVT,
                                                      short* __restrict__ Xb,
                                                      float* __restrict__ Op,
                                                      float* __restrict__ lp) {
  __shared__ __align__(16) char smem[36864];   // kbuf 12KB @0 | vbuf[2] 12KB @12288
  constexpr int ITERS = S_LEN / NKG / 64;
  int L = blockIdx.x;
  int bb = L & 511;
  int kg = L >> 9;
  int h = bb & 7, j = bb >> 3;
  int n = j >> 5, qt = j & 31;
  int q0 = qt * 128;
  int tid = threadIdx.x;
  int w = tid >> 6, lane = tid & 63, l31 = lane & 31, hi = lane >> 5;

  const float kAdj = 0.14724512f;  // (1/sqrt(96)) * log2(e), folded into Q
  bf16x8 qfa[6], qfb[6];
  #pragma unroll
  for (int sub = 0; sub < 2; ++sub) {
    const float* qp = Q + ((size_t)(n * S_LEN + q0 + w * 64 + sub * 32 + l31)) * EMB
                        + h * HDIM + 8 * hi;
    #pragma unroll
    for (int c = 0; c < 6; ++c) {
      float4 a = *(const float4*)(qp + 16 * c);
      float4 bq = *(const float4*)(qp + 16 * c + 4);
      bf16x8 r;
      r[0]=f2bf(a.x*kAdj);  r[1]=f2bf(a.y*kAdj);  r[2]=f2bf(a.z*kAdj);  r[3]=f2bf(a.w*kAdj);
      r[4]=f2bf(bq.x*kAdj); r[5]=f2bf(bq.y*kAdj); r[6]=f2bf(bq.z*kAdj); r[7]=f2bf(bq.w*kAdj);
      if (sub == 0) qfa[c] = r; else qfb[c] = r;
    }
  }

  // staging: wave w covers units w*6..w*6+5 of the K half and of the V half
  const short* gKV = KVT + ((size_t)((n * NHEAD + h) * 64 + kg * ITERS)) * 12288
                        + (size_t)(w * 6) * 512 + lane * 8;
  char* kbuf = smem;
  char* vbuf = smem + 12288;
  char* kdst = kbuf + w * 6144;
  char* vdst0 = vbuf + w * 6144;

  // prologue: stage K(0) + V(0)
  #pragma unroll
  for (int i = 0; i < 6; ++i) {
    GLOAD_LDS16(gKV + i * 512, kdst + i * 1024);
    GLOAD_LDS16(gKV + 6144 + i * 512, vdst0 + i * 1024);
  }
  __syncthreads();

  f32x16 oa[3], ob[3];
  #pragma unroll
  for (int dt = 0; dt < 3; ++dt) { oa[dt] = (f32x16){}; ob[dt] = (f32x16){}; }
  float tsa = 0.f, tsb = 0.f;

  int cur = 0;
  #pragma unroll 1
  for (int t = 0; t < ITERS; ++t) {
    // ---- QK^T: 4 independent chains (2 key-subtiles x 2 q-subtiles), K read once ----
    f32x16 s0a = (f32x16){}, s1a = (f32x16){}, s0b = (f32x16){}, s1b = (f32x16){};
    __builtin_amdgcn_s_setprio(1);
    #pragma unroll
    for (int c = 0; c < 6; ++c) {
      bf16x8 kf0 = *(const bf16x8*)(kbuf + c * 2048 + lane * 16);
      bf16x8 kf1 = *(const bf16x8*)(kbuf + c * 2048 + 1024 + lane * 16);
      s0a = __builtin_amdgcn_mfma_f32_32x32x16_bf16(kf0, qfa[c], s0a, 0, 0, 0);
      s0b = __builtin_amdgcn_mfma_f32_32x32x16_bf16(kf0, qfb[c], s0b, 0, 0, 0);
      s1a = __builtin_amdgcn_mfma_f32_32x32x16_bf16(kf1, qfa[c], s1a, 0, 0, 0);
      s1b = __builtin_amdgcn_mfma_f32_32x32x16_bf16(kf1, qfb[c], s1b, 0, 0, 0);
    }
    __builtin_amdgcn_s_setprio(0);
    __syncthreads();               // all K(t) reads complete; kbuf overwrite safe

    if (t < ITERS - 1) {           // stage K(t+1) -> kbuf, V(t+1) -> vbuf^1
      const short* src = gKV + (size_t)(t + 1) * 12288;
      char* vd = vbuf + (cur ^ 1) * 12288 + w * 6144;
      #pragma unroll
      for (int i = 0; i < 6; ++i) {
        GLOAD_LDS16(src + i * 512, kdst + i * 1024);
        GLOAD_LDS16(src + 6144 + i * 512, vd + i * 1024);
      }
    }

    // ---- P = 2^score; pairwise-tree row-sums ----
    #pragma unroll
    for (int r = 0; r < 16; ++r) s0a[r] = __builtin_amdgcn_exp2f(s0a[r]);
    #pragma unroll
    for (int r = 0; r < 16; ++r) s1a[r] = __builtin_amdgcn_exp2f(s1a[r]);
    #pragma unroll
    for (int r = 0; r < 16; ++r) s0b[r] = __builtin_amdgcn_exp2f(s0b[r]);
    #pragma unroll
    for (int r = 0; r < 16; ++r) s1b[r] = __builtin_amdgcn_exp2f(s1b[r]);
    {
      float a0 = (s0a[0]+s0a[1])+(s0a[2]+s0a[3]), a1 = (s0a[4]+s0a[5])+(s0a[6]+s0a[7]);
      float a2 = (s0a[8]+s0a[9])+(s0a[10]+s0a[11]), a3 = (s0a[12]+s0a[13])+(s0a[14]+s0a[15]);
      float b0 = (s1a[0]+s1a[1])+(s1a[2]+s1a[3]), b1 = (s1a[4]+s1a[5])+(s1a[6]+s1a[7]);
      float b2 = (s1a[8]+s1a[9])+(s1a[10]+s1a[11]), b3 = (s1a[12]+s1a[13])+(s1a[14]+s1a[15]);
      tsa += ((a0+a1)+(a2+a3)) + ((b0+b1)+(b2+b3));
      float c0 = (s0b[0]+s0b[1])+(s0b[2]+s0b[3]), c1 = (s0b[4]+s0b[5])+(s0b[6]+s0b[7]);
      float c2 = (s0b[8]+s0b[9])+(s0b[10]+s0b[11]), c3 = (s0b[12]+s0b[13])+(s0b[14]+s0b[15]);
      float d0_ = (s1b[0]+s1b[1])+(s1b[2]+s1b[3]), d1_ = (s1b[4]+s1b[5])+(s1b[6]+s1b[7]);
      float d2_ = (s1b[8]+s1b[9])+(s1b[10]+s1b[11]), d3_ = (s1b[12]+s1b[13])+(s1b[14]+s1b[15]);
      tsb += ((c0+c1)+(c2+c3)) + ((d0_+d1_)+(d2_+d3_));
    }

    // ---- pack (identity) + PV; V fragment read once serves both q-subtiles ----
    const char* vbl = vbuf + cur * 12288;
    #pragma unroll
    for (int ksub = 0; ksub < 2; ++ksub) {
      const f32x16& sa = ksub ? s1a : s0a;
      const f32x16& sb = ksub ? s1b : s0b;
      #pragma unroll
      for (int ks = 0; ks < 2; ++ks) {
        unsigned a0, a1, a2, a3, b0, b1, b2, b3;
        asm("v_cvt_pk_bf16_f32 %0, %1, %2" : "=v"(a0) : "v"(sa[8*ks+0]), "v"(sa[8*ks+1]));
        asm("v_cvt_pk_bf16_f32 %0, %1, %2" : "=v"(a1) : "v"(sa[8*ks+2]), "v"(sa[8*ks+3]));
        asm("v_cvt_pk_bf16_f32 %0, %1, %2" : "=v"(a2) : "v"(sa[8*ks+4]), "v"(sa[8*ks+5]));
        asm("v_cvt_pk_bf16_f32 %0, %1, %2" : "=v"(a3) : "v"(sa[8*ks+6]), "v"(sa[8*ks+7]));
        asm("v_cvt_pk_bf16_f32 %0, %1, %2" : "=v"(b0) : "v"(sb[8*ks+0]), "v"(sb[8*ks+1]));
        asm("v_cvt_pk_bf16_f32 %0, %1, %2" : "=v"(b1) : "v"(sb[8*ks+2]), "v"(sb[8*ks+3]));
        asm("v_cvt_pk_bf16_f32 %0, %1, %2" : "=v"(b2) : "v"(sb[8*ks+4]), "v"(sb[8*ks+5]));
        asm("v_cvt_pk_bf16_f32 %0, %1, %2" : "=v"(b3) : "v"(sb[8*ks+6]), "v"(sb[8*ks+7]));
        union { unsigned u[4]; bf16x8 v; } pa, pb;
        pa.u[0] = a0; pa.u[1] = a1; pa.u[2] = a2; pa.u[3] = a3;
        pb.u[0] = b0; pb.u[1] = b1; pb.u[2] = b2; pb.u[3] = b3;
        int slice = 2 * ksub + ks;
        __builtin_amdgcn_s_setprio(1);
        #pragma unroll
        for (int dt = 0; dt < 3; ++dt) {
          bf16x8 vf = *(const bf16x8*)(vbl + (slice * 3 + dt) * 1024 + hi * 512 + l31 * 16);
          oa[dt] = __builtin_amdgcn_mfma_f32_32x32x16_bf16(pa.v, vf, oa[dt], 0, 0, 0);
          ob[dt] = __builtin_amdgcn_mfma_f32_32x32x16_bf16(pb.v, vf, ob[dt], 0, 0, 0);
        }
        __builtin_amdgcn_s_setprio(0);
      }
    }
    __syncthreads();     // drains K(t+1)/V(t+1) staging (hidden under softmax+PV)
    cur ^= 1;
  }

  float la = tsa + __shfl_xor(tsa, 32, 64);
  float lb = tsb + __shfl_xor(tsb, 32, 64);

  if constexpr (NKG > 1) {
    // ---- partials: O (row-layout) + l (col-layout, row = l31) ----
    float* op = Op + (size_t)L * 12288;
    #pragma unroll
    for (int p = 0; p < 4; ++p) {
      #pragma unroll
      for (int jj = 0; jj < 4; ++jj) {
        int qra = w * 64 + 8 * p + 4 * hi + jj;
        op[(size_t)qra * 96 + l31]      = oa[0][4*p+jj];
        op[(size_t)qra * 96 + 32 + l31] = oa[1][4*p+jj];
        op[(size_t)qra * 96 + 64 + l31] = oa[2][4*p+jj];
        int qrb = qra + 32;
        op[(size_t)qrb * 96 + l31]      = ob[0][4*p+jj];
        op[(size_t)qrb * 96 + 32 + l31] = ob[1][4*p+jj];
        op[(size_t)qrb * 96 + 64 + l31] = ob[2][4*p+jj];
      }
    }
    if (hi == 0) {
      lp[(size_t)L * 128 + w * 64 + l31] = la;
      lp[(size_t)L * 128 + w * 64 + 32 + l31] = lb;
    }
  } else {
    __syncthreads();
    float* bcf = (float*)smem;
    if (hi == 0) {
      bcf[w * 64 + l31] = 1.0f / la;
      bcf[w * 64 + 32 + l31] = 1.0f / lb;
    }
    __syncthreads();
    #pragma unroll
    for (int p = 0; p < 4; ++p) {
      #pragma unroll
      for (int jj = 0; jj < 4; ++jj) {
        int qr = 8 * p + 4 * hi + jj;
        float iva = bcf[w * 64 + qr];
        float ivb = bcf[w * 64 + 32 + qr];
        short* xpa = Xb + ((size_t)(n * S_LEN + q0 + w * 64 + qr)) * EMB + h * HDIM + l31;
        xpa[0]  = f2bfh(oa[0][4*p+jj] * iva);
        xpa[32] = f2bfh(oa[1][4*p+jj] * iva);
        xpa[64] = f2bfh(oa[2][4*p+jj] * iva);
        short* xpb = xpa + (size_t)32 * EMB;
        xpb[0]  = f2bfh(ob[0][4*p+jj] * ivb);
        xpb[32] = f2bfh(ob[1][4*p+jj] * ivb);
        xpb[64] = f2bfh(ob[2][4*p+jj] * ivb);
      }
    }
  }
}

// ---------- split-K combine: Xb = (sum_kg O) / (sum_kg l), bf16 ----------
__global__ __launch_bounds__(256) void combine_kernel(const float* __restrict__ Op,
                                                      const float* __restrict__ lp,
                                                      short* __restrict__ Xb,
                                                      int nkg) {
  int b = blockIdx.x;
  int h = b & 7, j = b >> 3, n = j >> 5, qt = j & 31;
  int q0 = qt * 128;
  int tid = threadIdx.x;
  #pragma unroll 1
  for (int i = 0; i < 12; ++i) {
    int idx = (i * 256 + tid) * 4;
    int qr = idx / 96, d = idx - qr * 96;
    float ax = 0.f, ay = 0.f, az = 0.f, aw = 0.f, l = 0.f;
    for (int kg = 0; kg < nkg; ++kg) {
      size_t blk = (size_t)(kg * 512 + b);
      float4 v = *(const float4*)(Op + blk * 12288 + idx);
      ax += v.x; ay += v.y; az += v.z; aw += v.w;
      l += lp[blk * 128 + qr];
    }
    float iv = 1.0f / l;
    short4 r;
    r.x = f2bfh(ax * iv); r.y = f2bfh(ay * iv);
    r.z = f2bfh(az * iv); r.w = f2bfh(aw * iv);
    *(short4*)(Xb + ((size_t)(n * S_LEN + q0 + qr)) * EMB + h * HDIM + d) = r;
  }
}

// ---------- FC: out[m][j] = sum_k X[m][k] * W[j][k] + b[j] ----------
__global__ __launch_bounds__(256) void fc_kernel(const short* __restrict__ Xb,
                                                 const short* __restrict__ Wb,
                                                 const float* __restrict__ bias,
                                                 float* __restrict__ out) {
  int m0 = blockIdx.x * 64, j0 = blockIdx.y * 64;
  int tid = threadIdx.x;
  int w = tid >> 6, lane = tid & 63, lr = lane & 15, lg = lane >> 4;
  f32x4 acc[4];
  #pragma unroll
  for (int jt = 0; jt < 4; ++jt) acc[jt] = (f32x4){0.f, 0.f, 0.f, 0.f};
  const short* xp = Xb + (size_t)(m0 + w * 16 + lr) * EMB + 8 * lg;
  const short* wp = Wb + (size_t)(j0 + lr) * EMB + 8 * lg;
  #pragma unroll 1
  for (int kt = 0; kt < 24; ++kt) {
    bf16x8 a = *(const bf16x8*)(xp + kt * 32);
    #pragma unroll
    for (int jt = 0; jt < 4; ++jt) {
      bf16x8 bw = *(const bf16x8*)(wp + (size_t)(jt * 16) * EMB + kt * 32);
      acc[jt] = __builtin_amdgcn_mfma_f32_16x16x32_bf16(a, bw, acc[jt], 0, 0, 0);
    }
  }
  #pragma unroll
  for (int jt = 0; jt < 4; ++jt) {
    float bb = bias[j0 + jt * 16 + lr];
    #pragma unroll
    for (int i = 0; i < 4; ++i)
      out[(size_t)(m0 + w * 16 + 4 * lg + i) * EMB + j0 + jt * 16 + lr] = acc[jt][i] + bb;
  }
}

extern "C" void kernel_launch(void* const* d_in, const int* in_sizes, int n_in,
                              void* d_out, int out_size, void* d_ws, size_t ws_size,
                              hipStream_t stream) {
  (void)in_sizes; (void)n_in; (void)out_size;
  const float* V = (const float*)d_in[0];
  const float* K = (const float*)d_in[1];
  const float* Q = (const float*)d_in[2];
  const float* W = (const float*)d_in[3];
  const float* B = (const float*)d_in[4];
  float* out = (float*)d_out;
  // ws (shorts): KVT[12582912] | Wb[589824] | Xb[6291456] | partials (f32)
  short* KVT = (short*)d_ws;
  short* Wb  = KVT + 12582912;
  short* Xb  = Wb + 589824;
  size_t base_bytes = (size_t)(12582912 + 589824 + 6291456) * 2;
  size_t part_bytes = (size_t)2 * 512 * (12288 + 128) * 4;
  prep_kernel<<<2336, 256, 0, stream>>>(K, W, V, KVT, Wb);
  if (ws_size >= base_bytes + part_bytes) {
    float* Op = (float*)((char*)d_ws + base_bytes);
    float* lp = Op + (size_t)2 * 512 * 12288;
    attn_kernel<2><<<1024, 128, 0, stream>>>(Q, KVT, Xb, Op, lp);
    combine_kernel<<<512, 256, 0, stream>>>(Op, lp, Xb, 2);
  } else {
    attn_kernel<1><<<512, 128, 0, stream>>>(Q, KVT, Xb, nullptr, nullptr);
  }
  fc_kernel<<<dim3(128, 12), 256, 0, stream>>>(Xb, Wb, B, out);
}